// Round 3
// baseline (42359.644 us; speedup 1.0000x reference)
//
#include <hip/hip_runtime.h>
#include <hip/hip_bf16.h>
#include <math.h>

// Problem constants
#define Sn 3
#define Hn 64
#define Dn 12
#define Bn 512
#define Ln 512
#define BC 8            // batch elems per workgroup
#define IN0 76          // D + H
#define IN1 128         // 2H
#define NIN 22

using bf16 = __hip_bfloat16;

__device__ __forceinline__ float u2f(unsigned short x) {
    return __uint_as_float(((unsigned int)x) << 16);
}
__device__ __forceinline__ unsigned short f2u(float f) {
    bf16 h = __float2bfloat16(f);
    unsigned short u;
    __builtin_memcpy(&u, &h, 2);
    return u;
}
__device__ __forceinline__ float sigm(float x) { return 1.0f / (1.0f + expf(-x)); }
__device__ __forceinline__ float gelu_ex(float x) { return 0.5f * x * (1.0f + erff(x * 0.70710678118654752f)); }

__device__ __forceinline__ float redsum32(float v) {
    v += __shfl_xor(v, 16, 32);
    v += __shfl_xor(v, 8, 32);
    v += __shfl_xor(v, 4, 32);
    v += __shfl_xor(v, 2, 32);
    v += __shfl_xor(v, 1, 32);
    return v;
}
__device__ __forceinline__ float redsum64(float v) {
    v += __shfl_xor(v, 32, 64);
    v += __shfl_xor(v, 16, 64);
    v += __shfl_xor(v, 8, 64);
    v += __shfl_xor(v, 4, 64);
    v += __shfl_xor(v, 2, 64);
    v += __shfl_xor(v, 1, 64);
    return v;
}

// ---------------------------------------------------------------------------
// dtype detection: for bf16 payload every 16-bit half is a valid bf16 of an
// O(1) value (exp in [110,133]). For fp32 payload only high halves are (~55%).
// flag = 1 means inputs are fp32.  (Round-2 evidence: inputs ARE fp32.)
// ---------------------------------------------------------------------------
__global__ __launch_bounds__(256) void detect_kernel(const unsigned short* __restrict__ xr,
                                                     int* __restrict__ flag) {
    __shared__ int sh[4];
    int tid = threadIdx.x;
    int cnt = 0;
    for (int i = tid; i < 2048; i += 256) {
        unsigned e = (xr[i] >> 7) & 0xFF;
        if (e >= 110 && e <= 133) cnt++;
    }
    for (int o = 32; o > 0; o >>= 1) cnt += __shfl_xor(cnt, o, 64);
    if ((tid & 63) == 0) sh[tid >> 6] = cnt;
    __syncthreads();
    if (tid == 0) {
        int tot = sh[0] + sh[1] + sh[2] + sh[3];
        *flag = (tot < 1640) ? 1 : 0;
    }
}

// ---------------------------------------------------------------------------
// canonicalize all inputs to fp32 in ws
// ---------------------------------------------------------------------------
struct ConvArgs {
    const void* src[NIN];
    unsigned dstOff[NIN];
    unsigned n[NIN];
    unsigned blockStart[NIN + 1];
};

__global__ __launch_bounds__(256) void convert_kernel(ConvArgs a, float* __restrict__ dst,
                                                      const int* __restrict__ flag) {
    int bid = blockIdx.x;
    int i = 0;
    while (i < NIN - 1 && bid >= (int)a.blockStart[i + 1]) i++;
    unsigned lb = (unsigned)bid - a.blockStart[i];
    unsigned base = lb * 2048 + threadIdx.x;
    unsigned n = a.n[i];
    float* d = dst + a.dstOff[i];
    bool isf32 = (*flag != 0);
    const float* sf = (const float*)a.src[i];
    const unsigned short* su = (const unsigned short*)a.src[i];
#pragma unroll
    for (int e = 0; e < 8; e++) {
        unsigned idx = base + e * 256;
        if (idx < n) d[idx] = isf32 ? sf[idx] : u2f(su[idx]);
    }
}

// acc{A,B}[NC] += in{A,B}[k] * W[k][c], W row-major fp32 stride WS, pre-offset to col n0.
template <int NC, int KK, int WS>
__device__ __forceinline__ void mv(float* accA, float* accB,
                                   const float* __restrict__ inA,
                                   const float* __restrict__ inB,
                                   const float* __restrict__ Wn0) {
    for (int k = 0; k < KK; k += 4) {
        float4 a4 = *(const float4*)(inA + k);
        float4 b4 = *(const float4*)(inB + k);
        float av[4] = {a4.x, a4.y, a4.z, a4.w};
        float bv[4] = {b4.x, b4.y, b4.z, b4.w};
#pragma unroll
        for (int kk = 0; kk < 4; kk++) {
            const float* wp = Wn0 + (k + kk) * WS;
            float wv[4];
            if constexpr (NC == 4) {
                float4 w = *(const float4*)wp;
                wv[0] = w.x; wv[1] = w.y; wv[2] = w.z; wv[3] = w.w;
            } else if constexpr (NC == 2) {
                float2 w = *(const float2*)wp;
                wv[0] = w.x; wv[1] = w.y;
            } else {
                wv[0] = *wp;
            }
#pragma unroll
            for (int c = 0; c < NC; c++) {
                accA[c] = fmaf(av[kk], wv[c], accA[c]);
                accB[c] = fmaf(bv[kk], wv[c], accB[c]);
            }
        }
    }
}

// ---------------------------------------------------------------------------
// Setup: fuse  M1 = (mi_w[:,128:192] @ mo_w) @ w1   [64][128] fp32
//        bias1 = ((mi_b[128:192] @ mo_w + mo_b) @ w1 + b1)  [128] fp32
// grid = 6 (s*NL + l), block = 256
// ---------------------------------------------------------------------------
__global__ __launch_bounds__(256) void fuse_kernel(
    const float* __restrict__ mi_w, const float* __restrict__ mi_b,
    const float* __restrict__ mo_w, const float* __restrict__ mo_b,
    const float* __restrict__ w1, const float* __restrict__ b1,
    float* __restrict__ M1out, float* __restrict__ bias1out) {
    int sl = blockIdx.x;  // 0..5
    __shared__ float T[64][64];
    __shared__ float bT[64];
    const float* Mv = mi_w + sl * 64 * 192;  // [k][192], v-cols at +128
    const float* Mo = mo_w + sl * 64 * 64;   // [j][64]
    for (int idx = threadIdx.x; idx < 64 * 64; idx += 256) {
        int k = idx >> 6, n = idx & 63;
        float acc = 0.f;
        for (int j = 0; j < 64; j++) acc += Mv[k * 192 + 128 + j] * Mo[j * 64 + n];
        T[k][n] = acc;
    }
    for (int n = threadIdx.x; n < 64; n += 256) {
        float acc = mo_b[sl * 64 + n];
        for (int j = 0; j < 64; j++) acc += mi_b[sl * 192 + 128 + j] * Mo[j * 64 + n];
        bT[n] = acc;
    }
    __syncthreads();
    const float* W1 = w1 + sl * 64 * 128;  // [n][128]
    for (int idx = threadIdx.x; idx < 64 * 128; idx += 256) {
        int k = idx >> 7, m = idx & 127;
        float acc = 0.f;
        for (int n = 0; n < 64; n++) acc += T[k][n] * W1[n * 128 + m];
        M1out[sl * 64 * 128 + idx] = acc;
    }
    for (int m = threadIdx.x; m < 128; m += 256) {
        float acc = b1[sl * 128 + m];
        for (int n = 0; n < 64; n++) acc += bT[n] * W1[n * 128 + m];
        bias1out[sl * 128 + m] = acc;
    }
}

// ---------------------------------------------------------------------------
// Main persistent recurrent kernel.
// grid = 3*64 (scale, batch-chunk of 8), block = 256.
// ---------------------------------------------------------------------------
__global__ __launch_bounds__(256, 1) void xlstm_main(
    const float* __restrict__ x,     // [512][512][12]
    const float* __restrict__ gw0,   // [3][76][256]
    const float* __restrict__ gb0,   // [3][256]
    const float* __restrict__ gw1,   // [3][128][256]
    const float* __restrict__ gb1,   // [3][256]
    const float* __restrict__ w2,    // [3][2][128][64]
    const float* __restrict__ b2,    // [3][2][64]
    const float* __restrict__ lag, const float* __restrict__ lab,
    const float* __restrict__ log_, const float* __restrict__ lob,  // [3][2][64]
    const float* __restrict__ rw0,   // [3][12][64]
    const float* __restrict__ rb0,   // [3][64]
    const float* __restrict__ rw1,   // [3][64][64]
    const float* __restrict__ rb1,   // [3][64]
    const float* __restrict__ M1,    // ws [3][2][64][128] fp32
    const float* __restrict__ bias1, // ws [3][2][128] fp32
    unsigned short* __restrict__ merged) {  // ws [3][512][512][64] bf16
    const int tid = threadIdx.x;
    const int sIdx = blockIdx.x >> 6;
    const int chunk = blockIdx.x & 63;
    const int gbase = chunk * BC;

    // scale -> (Li, start): s0 uses ups[2] (Li=170,start=342), s1 identity, s2 (Li=256,start=256)
    const int Li = (sIdx == 0) ? 170 : (sIdx == 1 ? 512 : 256);
    const int st = (sIdx == 0) ? 342 : (sIdx == 1 ? 0 : 256);
    const float sc = (float)Li / 512.0f;

    __shared__ __align__(16) float s_gw0[IN0 * 256];  // 77824 B
    __shared__ float s_in0[BC][80];    // [x(12) | h0(64)] pad 80
    __shared__ float s_in1[BC][128];   // [inp(64) | h1(64)]
    __shared__ float s_g[BC][256];     // gates / z(0:128) / t2(128:192)
    __shared__ float s_ht[BC][64];
    __shared__ float s_c[2][BC][64];

    // load gw0 slice into LDS
    {
        const float4* src = (const float4*)(gw0 + sIdx * IN0 * 256);
        float4* dst = (float4*)s_gw0;
        for (int i = tid; i < IN0 * 256 / 4; i += 256) dst[i] = src[i];
    }
    // zero recurrent state
    for (int i = tid; i < BC * 64; i += 256) {
        int b = i >> 6, j = i & 63;
        s_in0[b][12 + j] = 0.f;
        s_in1[b][64 + j] = 0.f;
        s_c[0][b][j] = 0.f;
        s_c[1][b][j] = 0.f;
    }
    __syncthreads();

    // matvec mapping: 64 col-groups x 4 batch-pair-groups
    const int cg = tid & 63, bg = tid >> 6;
    const int n4 = cg * 4, n2 = cg * 2, n1 = cg;
    const int bA = bg * 2, bB = bg * 2 + 1;
    // per-unit mapping: 8 batches x 32 lane-halves, 2 units each
    const int ub = tid >> 5, uj = (tid & 31) * 2;

    // hoisted per-thread constants
    float h_gb0[4], h_gb1[4];
    {
        float4 u = *(const float4*)(gb0 + sIdx * 256 + n4);
        h_gb0[0] = u.x; h_gb0[1] = u.y; h_gb0[2] = u.z; h_gb0[3] = u.w;
        float4 v = *(const float4*)(gb1 + sIdx * 256 + n4);
        h_gb1[0] = v.x; h_gb1[1] = v.y; h_gb1[2] = v.z; h_gb1[3] = v.w;
    }
    float h_b1[2][2], h_b2[2], h_rb1;
    for (int l = 0; l < 2; l++) {
        h_b1[l][0] = bias1[(sIdx * 2 + l) * 128 + n2];
        h_b1[l][1] = bias1[(sIdx * 2 + l) * 128 + n2 + 1];
        h_b2[l] = b2[(sIdx * 2 + l) * 64 + n1];
    }
    h_rb1 = rb1[sIdx * 64 + n1];
    float h_lag0[2], h_lab0[2], h_log0[2], h_lob0[2];
    float h_lag1[2], h_lab1[2], h_log1[2], h_lob1[2];
    float h_rb0[2], h_rw0[12][2];
    {
        int b0i = (sIdx * 2 + 0) * 64 + uj;
        int b1i = (sIdx * 2 + 1) * 64 + uj;
#pragma unroll
        for (int u = 0; u < 2; u++) {
            h_lag0[u] = lag[b0i + u]; h_lab0[u] = lab[b0i + u];
            h_log0[u] = log_[b0i + u]; h_lob0[u] = lob[b0i + u];
            h_lag1[u] = lag[b1i + u]; h_lab1[u] = lab[b1i + u];
            h_log1[u] = log_[b1i + u]; h_lob1[u] = lob[b1i + u];
            h_rb0[u] = rb0[sIdx * 64 + uj + u];
        }
#pragma unroll
        for (int d = 0; d < 12; d++) {
            h_rw0[d][0] = rw0[(sIdx * 12 + d) * 64 + uj];
            h_rw0[d][1] = rw0[(sIdx * 12 + d) * 64 + uj + 1];
        }
    }

    const float* pgw1 = gw1 + sIdx * 128 * 256;
    const float* pM1a = M1 + (sIdx * 2 + 0) * 64 * 128 + n2;
    const float* pM1b = M1 + (sIdx * 2 + 1) * 64 * 128 + n2;
    const float* pw2a = w2 + (sIdx * 2 + 0) * 128 * 64 + n1;
    const float* pw2b = w2 + (sIdx * 2 + 1) * 128 * 64 + n1;
    const float* prw1 = rw1 + sIdx * 64 * 64 + n1;

    for (int t = 0; t < Ln; t++) {
        // phase 1: upsampled x_t -> s_in0[b][0..12)
        if (tid < BC * 12) {
            int b = tid / 12, d = tid % 12;
            float src = (t + 0.5f) * sc - 0.5f;
            src = fmaxf(src, 0.f);
            int i0 = (int)floorf(src);
            if (i0 > Li - 1) i0 = Li - 1;
            int i1 = i0 + 1;
            if (i1 > Li - 1) i1 = Li - 1;
            float w = src - (float)i0;
            int gb = gbase + b;
            float v0 = x[(gb * Ln + st + i0) * 12 + d];
            float v1 = x[(gb * Ln + st + i1) * 12 + d];
            s_in0[b][d] = v0 * (1.0f - w) + v1 * w;
        }
        __syncthreads();

        // ===== layer 0 =====
        {  // gates0 = [x|h0] @ gw0 + gb0
            float aA[4] = {h_gb0[0], h_gb0[1], h_gb0[2], h_gb0[3]};
            float aB[4] = {h_gb0[0], h_gb0[1], h_gb0[2], h_gb0[3]};
            mv<4, IN0, 256>(aA, aB, &s_in0[bA][0], &s_in0[bB][0], s_gw0 + n4);
            float4 rA; rA.x = aA[0]; rA.y = aA[1]; rA.z = aA[2]; rA.w = aA[3];
            float4 rB; rB.x = aB[0]; rB.y = aB[1]; rB.z = aB[2]; rB.w = aB[3];
            *(float4*)&s_g[bA][n4] = rA;
            *(float4*)&s_g[bB][n4] = rB;
        }
        __syncthreads();
        {  // cell update 0
            float f0 = s_g[ub][uj], f1 = s_g[ub][uj + 1];
            float i0v = s_g[ub][64 + uj], i1v = s_g[ub][64 + uj + 1];
            float g0 = s_g[ub][128 + uj], g1 = s_g[ub][128 + uj + 1];
            float o0 = s_g[ub][192 + uj], o1 = s_g[ub][192 + uj + 1];
            float c0 = s_c[0][ub][uj], c1 = s_c[0][ub][uj + 1];
            float cn0 = sigm(f0) * c0 + sigm(i0v) * tanhf(g0);
            float cn1 = sigm(f1) * c1 + sigm(i1v) * tanhf(g1);
            s_c[0][ub][uj] = cn0; s_c[0][ub][uj + 1] = cn1;
            s_ht[ub][uj] = sigm(o0) * tanhf(cn0);
            s_ht[ub][uj + 1] = sigm(o1) * tanhf(cn1);
        }
        __syncthreads();
        {  // z = gelu(ht @ M1_0 + bias1_0) -> s_g[b][0..128)
            float aA[2] = {h_b1[0][0], h_b1[0][1]};
            float aB[2] = {h_b1[0][0], h_b1[0][1]};
            mv<2, 64, 128>(aA, aB, &s_ht[bA][0], &s_ht[bB][0], pM1a);
            s_g[bA][n2] = gelu_ex(aA[0]); s_g[bA][n2 + 1] = gelu_ex(aA[1]);
            s_g[bB][n2] = gelu_ex(aB[0]); s_g[bB][n2 + 1] = gelu_ex(aB[1]);
        }
        __syncthreads();
        {  // t2 = z @ w2_0 + b2_0 -> s_g[b][128+n]
            float aA[1] = {h_b2[0]}, aB[1] = {h_b2[0]};
            mv<1, 128, 64>(aA, aB, &s_g[bA][0], &s_g[bB][0], pw2a);
            s_g[bA][128 + n1] = aA[0];
            s_g[bB][128 + n1] = aB[0];
        }
        __syncthreads();
        {  // LN chain 0 + inp
            float v0 = s_g[ub][128 + uj], v1 = s_g[ub][128 + uj + 1];
            float m = redsum32(v0 + v1) * (1.0f / 64.0f);
            float var = redsum32(v0 * v0 + v1 * v1) * (1.0f / 64.0f) - m * m;
            float rs = rsqrtf(fmaxf(var, 0.0f) + 1e-5f);
            float a0 = (v0 - m) * rs * h_lag0[0] + h_lab0[0];
            float a1 = (v1 - m) * rs * h_lag0[1] + h_lab0[1];
            float y0 = a0 + s_in0[ub][12 + uj];
            float y1 = a1 + s_in0[ub][12 + uj + 1];
            float m2 = redsum32(y0 + y1) * (1.0f / 64.0f);
            float var2 = redsum32(y0 * y0 + y1 * y1) * (1.0f / 64.0f) - m2 * m2;
            float rs2 = rsqrtf(fmaxf(var2, 0.0f) + 1e-5f);
            float h0n0 = (y0 - m2) * rs2 * h_log0[0] + h_lob0[0];
            float h0n1 = (y1 - m2) * rs2 * h_log0[1] + h_lob0[1];
            s_in0[ub][12 + uj] = h0n0;
            s_in0[ub][12 + uj + 1] = h0n1;
            float p0 = h0n0 + h_rb0[0], p1 = h0n1 + h_rb0[1];
#pragma unroll
            for (int d = 0; d < 12; d++) {
                float xv = s_in0[ub][d];
                p0 = fmaf(xv, h_rw0[d][0], p0);
                p1 = fmaf(xv, h_rw0[d][1], p1);
            }
            s_in1[ub][uj] = p0;
            s_in1[ub][uj + 1] = p1;
        }
        __syncthreads();

        // ===== layer 1 =====
        {  // gates1 = [inp|h1] @ gw1 + gb1
            float aA[4] = {h_gb1[0], h_gb1[1], h_gb1[2], h_gb1[3]};
            float aB[4] = {h_gb1[0], h_gb1[1], h_gb1[2], h_gb1[3]};
            mv<4, IN1, 256>(aA, aB, &s_in1[bA][0], &s_in1[bB][0], pgw1 + n4);
            float4 rA; rA.x = aA[0]; rA.y = aA[1]; rA.z = aA[2]; rA.w = aA[3];
            float4 rB; rB.x = aB[0]; rB.y = aB[1]; rB.z = aB[2]; rB.w = aB[3];
            *(float4*)&s_g[bA][n4] = rA;
            *(float4*)&s_g[bB][n4] = rB;
        }
        __syncthreads();
        {  // cell update 1
            float f0 = s_g[ub][uj], f1 = s_g[ub][uj + 1];
            float i0v = s_g[ub][64 + uj], i1v = s_g[ub][64 + uj + 1];
            float g0 = s_g[ub][128 + uj], g1 = s_g[ub][128 + uj + 1];
            float o0 = s_g[ub][192 + uj], o1 = s_g[ub][192 + uj + 1];
            float c0 = s_c[1][ub][uj], c1 = s_c[1][ub][uj + 1];
            float cn0 = sigm(f0) * c0 + sigm(i0v) * tanhf(g0);
            float cn1 = sigm(f1) * c1 + sigm(i1v) * tanhf(g1);
            s_c[1][ub][uj] = cn0; s_c[1][ub][uj + 1] = cn1;
            s_ht[ub][uj] = sigm(o0) * tanhf(cn0);
            s_ht[ub][uj + 1] = sigm(o1) * tanhf(cn1);
        }
        __syncthreads();
        {  // z = gelu(ht @ M1_1 + bias1_1)
            float aA[2] = {h_b1[1][0], h_b1[1][1]};
            float aB[2] = {h_b1[1][0], h_b1[1][1]};
            mv<2, 64, 128>(aA, aB, &s_ht[bA][0], &s_ht[bB][0], pM1b);
            s_g[bA][n2] = gelu_ex(aA[0]); s_g[bA][n2 + 1] = gelu_ex(aA[1]);
            s_g[bB][n2] = gelu_ex(aB[0]); s_g[bB][n2 + 1] = gelu_ex(aB[1]);
        }
        __syncthreads();
        {  // t2 = z @ w2_1 + b2_1
            float aA[1] = {h_b2[1]}, aB[1] = {h_b2[1]};
            mv<1, 128, 64>(aA, aB, &s_g[bA][0], &s_g[bB][0], pw2b);
            s_g[bA][128 + n1] = aA[0];
            s_g[bB][128 + n1] = aB[0];
        }
        __syncthreads();
        {  // LN chain 1 -> h1_new
            float v0 = s_g[ub][128 + uj], v1 = s_g[ub][128 + uj + 1];
            float m = redsum32(v0 + v1) * (1.0f / 64.0f);
            float var = redsum32(v0 * v0 + v1 * v1) * (1.0f / 64.0f) - m * m;
            float rs = rsqrtf(fmaxf(var, 0.0f) + 1e-5f);
            float a0 = (v0 - m) * rs * h_lag1[0] + h_lab1[0];
            float a1 = (v1 - m) * rs * h_lag1[1] + h_lab1[1];
            float y0 = a0 + s_in1[ub][64 + uj];
            float y1 = a1 + s_in1[ub][64 + uj + 1];
            float m2 = redsum32(y0 + y1) * (1.0f / 64.0f);
            float var2 = redsum32(y0 * y0 + y1 * y1) * (1.0f / 64.0f) - m2 * m2;
            float rs2 = rsqrtf(fmaxf(var2, 0.0f) + 1e-5f);
            s_in1[ub][64 + uj] = (y0 - m2) * rs2 * h_log1[0] + h_lob1[0];
            s_in1[ub][64 + uj + 1] = (y1 - m2) * rs2 * h_log1[1] + h_lob1[1];
        }
        __syncthreads();
        {  // out = h1_new + inp @ rw1 + rb1 -> merged (bf16)
            float aA[1] = {s_in1[bA][64 + n1] + h_rb1};
            float aB[1] = {s_in1[bB][64 + n1] + h_rb1};
            mv<1, 64, 64>(aA, aB, &s_in1[bA][0], &s_in1[bB][0], prw1);
            unsigned int base = (((unsigned)(sIdx * Bn + gbase + bA) * Ln) + t) * 64 + n1;
            merged[base] = f2u(aA[0]);
            merged[base + (unsigned)Ln * 64] = f2u(aB[0]);
        }
        __syncthreads();
    }
}

// ---------------------------------------------------------------------------
// Combine: softmax over scales of (merged . attn_w), weighted sum -> out
// wave per (b,t); grid = B*L/4, block = 256. Output dtype chosen by flag.
// ---------------------------------------------------------------------------
__global__ __launch_bounds__(256) void combine_kernel(
    const unsigned short* __restrict__ merged,
    const float* __restrict__ attn_w,
    void* __restrict__ outv, const int* __restrict__ flag) {
    int wid = (blockIdx.x << 2) + (threadIdx.x >> 6);
    int lane = threadIdx.x & 63;
    int b = wid >> 9, t = wid & 511;
    float aw = attn_w[lane];
    unsigned int stride = (unsigned)Bn * Ln * 64;
    unsigned int base = (((unsigned)b * Ln) + t) * 64 + lane;
    float m0 = u2f(merged[base]);
    float m1 = u2f(merged[base + stride]);
    float m2 = u2f(merged[base + 2 * stride]);
    float e0 = redsum64(m0 * aw);
    float e1 = redsum64(m1 * aw);
    float e2 = redsum64(m2 * aw);
    float mx = fmaxf(e0, fmaxf(e1, e2));
    float x0 = expf(e0 - mx), x1 = expf(e1 - mx), x2 = expf(e2 - mx);
    float inv = 1.0f / (x0 + x1 + x2);
    float val = (x0 * m0 + x1 * m1 + x2 * m2) * inv;
    if (*flag) ((float*)outv)[base] = val;
    else ((unsigned short*)outv)[base] = f2u(val);
}

extern "C" void kernel_launch(void* const* d_in, const int* in_sizes, int n_in,
                              void* d_out, int out_size, void* d_ws, size_t ws_size,
                              hipStream_t stream) {
    (void)out_size; (void)ws_size;
    // ---- ws layout ----
    // [0..16): flag int | canonical fp32 inputs | M1 fp32 | bias1 fp32 | merged bf16
    int* flag = (int*)d_ws;
    float* canon = (float*)((char*)d_ws + 16);

    ConvArgs ca;
    size_t tot = 0;
    unsigned nblocks = 0;
    for (int i = 0; i < NIN; i++) {
        ca.src[i] = d_in[i];
        ca.dstOff[i] = (unsigned)tot;
        unsigned n = (unsigned)in_sizes[i];
        ca.n[i] = n;
        ca.blockStart[i] = nblocks;
        nblocks += (n + 2047) / 2048;
        tot += n;
    }
    ca.blockStart[NIN] = nblocks;

    size_t canonBytes = (tot * 4 + 15) & ~(size_t)15;
    char* p = (char*)d_ws + 16 + canonBytes;
    float* M1 = (float*)p; p += (size_t)3 * 2 * 64 * 128 * 4;
    float* bias1 = (float*)p; p += (size_t)3 * 2 * 128 * 4;
    p = (char*)(((uintptr_t)p + 15) & ~(uintptr_t)15);
    unsigned short* merged = (unsigned short*)p;

    // canonical input pointers (element offsets into canon)
    const float* x    = canon + ca.dstOff[0];
    const float* gw0  = canon + ca.dstOff[1];
    const float* gb0  = canon + ca.dstOff[2];
    const float* gw1  = canon + ca.dstOff[3];
    const float* gb1  = canon + ca.dstOff[4];
    const float* mi_w = canon + ca.dstOff[5];
    const float* mi_b = canon + ca.dstOff[6];
    const float* mo_w = canon + ca.dstOff[7];
    const float* mo_b = canon + ca.dstOff[8];
    const float* w1   = canon + ca.dstOff[9];
    const float* b1   = canon + ca.dstOff[10];
    const float* w2   = canon + ca.dstOff[11];
    const float* b2   = canon + ca.dstOff[12];
    const float* lag  = canon + ca.dstOff[13];
    const float* lab  = canon + ca.dstOff[14];
    const float* log_ = canon + ca.dstOff[15];
    const float* lob  = canon + ca.dstOff[16];
    const float* rw0  = canon + ca.dstOff[17];
    const float* rb0  = canon + ca.dstOff[18];
    const float* rw1  = canon + ca.dstOff[19];
    const float* rb1  = canon + ca.dstOff[20];
    const float* attn_w = canon + ca.dstOff[21];

    detect_kernel<<<dim3(1), dim3(256), 0, stream>>>((const unsigned short*)d_in[0], flag);
    convert_kernel<<<dim3(nblocks), dim3(256), 0, stream>>>(ca, canon, flag);
    fuse_kernel<<<dim3(6), dim3(256), 0, stream>>>(mi_w, mi_b, mo_w, mo_b, w1, b1, M1, bias1);
    xlstm_main<<<dim3(Sn * (Bn / BC)), dim3(256), 0, stream>>>(
        x, gw0, gb0, gw1, gb1, w2, b2, lag, lab, log_, lob,
        rw0, rb0, rw1, rb1, M1, bias1, merged);
    combine_kernel<<<dim3(Bn * Ln / 4), dim3(256), 0, stream>>>(merged, attn_w, d_out, flag);
}

// Round 4
// 7579.637 us; speedup vs baseline: 5.5886x; 5.5886x over previous
//
#include <hip/hip_runtime.h>
#include <hip/hip_bf16.h>
#include <math.h>

// Problem constants
#define Sn 3
#define Hn 64
#define Dn 12
#define Bn 512
#define Ln 512
#define BC 8            // batch elems per workgroup
#define IN0 76          // D + H
#define NIN 22
#define CT 32           // timesteps per chunk
#define NCHUNK (Ln / CT)

using bf16 = __hip_bfloat16;

__device__ __forceinline__ float u2f(unsigned short x) {
    return __uint_as_float(((unsigned int)x) << 16);
}
__device__ __forceinline__ unsigned short f2u(float f) {
    bf16 h = __float2bfloat16(f);
    unsigned short u;
    __builtin_memcpy(&u, &h, 2);
    return u;
}
__device__ __forceinline__ float sigm(float x) { return 1.0f / (1.0f + expf(-x)); }
__device__ __forceinline__ float gelu_ex(float x) { return 0.5f * x * (1.0f + erff(x * 0.70710678118654752f)); }

__device__ __forceinline__ float redsum32(float v) {
    v += __shfl_xor(v, 16, 32);
    v += __shfl_xor(v, 8, 32);
    v += __shfl_xor(v, 4, 32);
    v += __shfl_xor(v, 2, 32);
    v += __shfl_xor(v, 1, 32);
    return v;
}
__device__ __forceinline__ float redsum64(float v) {
    v += __shfl_xor(v, 32, 64);
    v += __shfl_xor(v, 16, 64);
    v += __shfl_xor(v, 8, 64);
    v += __shfl_xor(v, 4, 64);
    v += __shfl_xor(v, 2, 64);
    v += __shfl_xor(v, 1, 64);
    return v;
}

// ---------------------------------------------------------------------------
// dtype detection (flag=1 -> inputs fp32). Round-3: inputs ARE fp32.
// ---------------------------------------------------------------------------
__global__ __launch_bounds__(256) void detect_kernel(const unsigned short* __restrict__ xr,
                                                     int* __restrict__ flag) {
    __shared__ int sh[4];
    int tid = threadIdx.x;
    int cnt = 0;
    for (int i = tid; i < 2048; i += 256) {
        unsigned e = (xr[i] >> 7) & 0xFF;
        if (e >= 110 && e <= 133) cnt++;
    }
    for (int o = 32; o > 0; o >>= 1) cnt += __shfl_xor(cnt, o, 64);
    if ((tid & 63) == 0) sh[tid >> 6] = cnt;
    __syncthreads();
    if (tid == 0) {
        int tot = sh[0] + sh[1] + sh[2] + sh[3];
        *flag = (tot < 1640) ? 1 : 0;
    }
}

// ---------------------------------------------------------------------------
// canonicalize all inputs to fp32 in ws
// ---------------------------------------------------------------------------
struct ConvArgs {
    const void* src[NIN];
    unsigned dstOff[NIN];
    unsigned n[NIN];
    unsigned blockStart[NIN + 1];
};

__global__ __launch_bounds__(256) void convert_kernel(ConvArgs a, float* __restrict__ dst,
                                                      const int* __restrict__ flag) {
    int bid = blockIdx.x;
    int i = 0;
    while (i < NIN - 1 && bid >= (int)a.blockStart[i + 1]) i++;
    unsigned lb = (unsigned)bid - a.blockStart[i];
    unsigned base = lb * 2048 + threadIdx.x;
    unsigned n = a.n[i];
    float* d = dst + a.dstOff[i];
    bool isf32 = (*flag != 0);
    const float* sf = (const float*)a.src[i];
    const unsigned short* su = (const unsigned short*)a.src[i];
#pragma unroll
    for (int e = 0; e < 8; e++) {
        unsigned idx = base + e * 256;
        if (idx < n) d[idx] = isf32 ? sf[idx] : u2f(su[idx]);
    }
}

// acc{A,B}[NC] += in{A,B}[k] * W[k][c], W row-major fp32 stride WS, pre-offset to col n0.
template <int NC, int KK, int WS>
__device__ __forceinline__ void mv(float* accA, float* accB,
                                   const float* __restrict__ inA,
                                   const float* __restrict__ inB,
                                   const float* __restrict__ Wn0) {
    for (int k = 0; k < KK; k += 4) {
        float4 a4 = *(const float4*)(inA + k);
        float4 b4 = *(const float4*)(inB + k);
        float av[4] = {a4.x, a4.y, a4.z, a4.w};
        float bv[4] = {b4.x, b4.y, b4.z, b4.w};
#pragma unroll
        for (int kk = 0; kk < 4; kk++) {
            const float* wp = Wn0 + (k + kk) * WS;
            float wv[4];
            if constexpr (NC == 4) {
                float4 w = *(const float4*)wp;
                wv[0] = w.x; wv[1] = w.y; wv[2] = w.z; wv[3] = w.w;
            } else if constexpr (NC == 2) {
                float2 w = *(const float2*)wp;
                wv[0] = w.x; wv[1] = w.y;
            } else {
                wv[0] = *wp;
            }
#pragma unroll
            for (int c = 0; c < NC; c++) {
                accA[c] = fmaf(av[kk], wv[c], accA[c]);
                accB[c] = fmaf(bv[kk], wv[c], accB[c]);
            }
        }
    }
}

// ---------------------------------------------------------------------------
// Setup: fuse  M1 = (mi_w[:,128:192] @ mo_w) @ w1   [64][128] fp32
//        bias1 = ((mi_b[128:192] @ mo_w + mo_b) @ w1 + b1)  [128] fp32
// ---------------------------------------------------------------------------
__global__ __launch_bounds__(256) void fuse_kernel(
    const float* __restrict__ mi_w, const float* __restrict__ mi_b,
    const float* __restrict__ mo_w, const float* __restrict__ mo_b,
    const float* __restrict__ w1, const float* __restrict__ b1,
    float* __restrict__ M1out, float* __restrict__ bias1out) {
    int sl = blockIdx.x;  // 0..5
    __shared__ float T[64][64];
    __shared__ float bT[64];
    const float* Mv = mi_w + sl * 64 * 192;
    const float* Mo = mo_w + sl * 64 * 64;
    for (int idx = threadIdx.x; idx < 64 * 64; idx += 256) {
        int k = idx >> 6, n = idx & 63;
        float acc = 0.f;
        for (int j = 0; j < 64; j++) acc += Mv[k * 192 + 128 + j] * Mo[j * 64 + n];
        T[k][n] = acc;
    }
    for (int n = threadIdx.x; n < 64; n += 256) {
        float acc = mo_b[sl * 64 + n];
        for (int j = 0; j < 64; j++) acc += mi_b[sl * 192 + 128 + j] * Mo[j * 64 + n];
        bT[n] = acc;
    }
    __syncthreads();
    const float* W1 = w1 + sl * 64 * 128;
    for (int idx = threadIdx.x; idx < 64 * 128; idx += 256) {
        int k = idx >> 7, m = idx & 127;
        float acc = 0.f;
        for (int n = 0; n < 64; n++) acc += T[k][n] * W1[n * 128 + m];
        M1out[sl * 64 * 128 + idx] = acc;
    }
    for (int m = threadIdx.x; m < 128; m += 256) {
        float acc = b1[sl * 128 + m];
        for (int n = 0; n < 64; n++) acc += bT[n] * W1[n * 128 + m];
        bias1out[sl * 128 + m] = acc;
    }
}

// ---------------------------------------------------------------------------
// Pass 1: layer 0 over a T-chunk. All weights LDS-resident.
// grid = 3*64, block = 256.
// ---------------------------------------------------------------------------
__global__ __launch_bounds__(256, 1) void pass1_kernel(
    const float* __restrict__ x,      // [512][512][12]
    const float* __restrict__ gw0,    // [3][76][256]
    const float* __restrict__ gb0,    // [3][256]
    const float* __restrict__ M1g,    // [3][2][64][128]
    const float* __restrict__ bias1g, // [3][2][128]
    const float* __restrict__ w2g,    // [3][2][128][64]
    const float* __restrict__ b2g,
    const float* __restrict__ lag, const float* __restrict__ lab,
    const float* __restrict__ log_, const float* __restrict__ lob,
    const float* __restrict__ rw0,    // [3][12][64]
    const float* __restrict__ rb0,    // [3][64]
    float* __restrict__ gstate,       // [3][512][4][64]  (h0,c0,h1,c1)
    float* __restrict__ inp_c,        // [3][512][CT][64]
    int t0) {
    const int tid = threadIdx.x;
    const int sIdx = blockIdx.x >> 6;
    const int gbase = (blockIdx.x & 63) * BC;

    const int Li = (sIdx == 0) ? 170 : (sIdx == 1 ? 512 : 256);
    const int st = (sIdx == 0) ? 342 : (sIdx == 1 ? 0 : 256);
    const float sc = (float)Li / 512.0f;

    __shared__ __align__(16) float s_gw0[IN0 * 256];   // 77824 B
    __shared__ __align__(16) float s_M1[64 * 128];     // 32768
    __shared__ __align__(16) float s_w2[128 * 64];     // 32768
    __shared__ float s_in0[BC][80];
    __shared__ float s_g[BC][256];
    __shared__ float s_ht[BC][64];
    __shared__ float s_c[BC][64];

    {
        const float4* src = (const float4*)(gw0 + sIdx * IN0 * 256);
        for (int i = tid; i < IN0 * 256 / 4; i += 256) ((float4*)s_gw0)[i] = src[i];
        src = (const float4*)(M1g + (sIdx * 2 + 0) * 64 * 128);
        for (int i = tid; i < 64 * 128 / 4; i += 256) ((float4*)s_M1)[i] = src[i];
        src = (const float4*)(w2g + (sIdx * 2 + 0) * 128 * 64);
        for (int i = tid; i < 128 * 64 / 4; i += 256) ((float4*)s_w2)[i] = src[i];
    }
    for (int i = tid; i < BC * 64; i += 256) {
        int b = i >> 6, j = i & 63;
        if (t0 == 0) {
            s_in0[b][12 + j] = 0.f;
            s_c[b][j] = 0.f;
        } else {
            const float* gs = gstate + ((size_t)(sIdx * Bn + gbase + b)) * 256;
            s_in0[b][12 + j] = gs[j];
            s_c[b][j] = gs[64 + j];
        }
    }
    __syncthreads();

    const int cg = tid & 63, bg = tid >> 6;
    const int n4 = cg * 4, n2 = cg * 2, n1 = cg;
    const int bA = bg * 2, bB = bg * 2 + 1;
    const int ub = tid >> 5, uj = (tid & 31) * 2;

    float h_gb0[4];
    {
        float4 u = *(const float4*)(gb0 + sIdx * 256 + n4);
        h_gb0[0] = u.x; h_gb0[1] = u.y; h_gb0[2] = u.z; h_gb0[3] = u.w;
    }
    float h_b1[2], h_b2;
    h_b1[0] = bias1g[(sIdx * 2 + 0) * 128 + n2];
    h_b1[1] = bias1g[(sIdx * 2 + 0) * 128 + n2 + 1];
    h_b2 = b2g[(sIdx * 2 + 0) * 64 + n1];
    float h_lag0[2], h_lab0[2], h_log0[2], h_lob0[2], h_rb0[2], h_rw0[12][2];
    {
        int bi = (sIdx * 2 + 0) * 64 + uj;
#pragma unroll
        for (int u = 0; u < 2; u++) {
            h_lag0[u] = lag[bi + u]; h_lab0[u] = lab[bi + u];
            h_log0[u] = log_[bi + u]; h_lob0[u] = lob[bi + u];
            h_rb0[u] = rb0[sIdx * 64 + uj + u];
        }
#pragma unroll
        for (int d = 0; d < 12; d++) {
            h_rw0[d][0] = rw0[(sIdx * 12 + d) * 64 + uj];
            h_rw0[d][1] = rw0[(sIdx * 12 + d) * 64 + uj + 1];
        }
    }

    for (int tt = 0; tt < CT; tt++) {
        int t = t0 + tt;
        if (tid < BC * 12) {
            int b = tid / 12, d = tid % 12;
            float src = (t + 0.5f) * sc - 0.5f;
            src = fmaxf(src, 0.f);
            int i0 = (int)floorf(src);
            if (i0 > Li - 1) i0 = Li - 1;
            int i1 = i0 + 1;
            if (i1 > Li - 1) i1 = Li - 1;
            float w = src - (float)i0;
            int gb = gbase + b;
            float v0 = x[(gb * Ln + st + i0) * 12 + d];
            float v1 = x[(gb * Ln + st + i1) * 12 + d];
            s_in0[b][d] = v0 * (1.0f - w) + v1 * w;
        }
        __syncthreads();
        {  // gates0
            float aA[4] = {h_gb0[0], h_gb0[1], h_gb0[2], h_gb0[3]};
            float aB[4] = {h_gb0[0], h_gb0[1], h_gb0[2], h_gb0[3]};
            mv<4, IN0, 256>(aA, aB, &s_in0[bA][0], &s_in0[bB][0], s_gw0 + n4);
            float4 rA; rA.x = aA[0]; rA.y = aA[1]; rA.z = aA[2]; rA.w = aA[3];
            float4 rB; rB.x = aB[0]; rB.y = aB[1]; rB.z = aB[2]; rB.w = aB[3];
            *(float4*)&s_g[bA][n4] = rA;
            *(float4*)&s_g[bB][n4] = rB;
        }
        __syncthreads();
        {  // cell0
            float f0 = s_g[ub][uj], f1 = s_g[ub][uj + 1];
            float i0v = s_g[ub][64 + uj], i1v = s_g[ub][64 + uj + 1];
            float g0 = s_g[ub][128 + uj], g1 = s_g[ub][128 + uj + 1];
            float o0 = s_g[ub][192 + uj], o1 = s_g[ub][192 + uj + 1];
            float c0 = s_c[ub][uj], c1 = s_c[ub][uj + 1];
            float cn0 = sigm(f0) * c0 + sigm(i0v) * tanhf(g0);
            float cn1 = sigm(f1) * c1 + sigm(i1v) * tanhf(g1);
            s_c[ub][uj] = cn0; s_c[ub][uj + 1] = cn1;
            s_ht[ub][uj] = sigm(o0) * tanhf(cn0);
            s_ht[ub][uj + 1] = sigm(o1) * tanhf(cn1);
        }
        __syncthreads();
        {  // z = gelu(ht @ M1_0 + bias1_0)
            float aA[2] = {h_b1[0], h_b1[1]};
            float aB[2] = {h_b1[0], h_b1[1]};
            mv<2, 64, 128>(aA, aB, &s_ht[bA][0], &s_ht[bB][0], s_M1 + n2);
            s_g[bA][n2] = gelu_ex(aA[0]); s_g[bA][n2 + 1] = gelu_ex(aA[1]);
            s_g[bB][n2] = gelu_ex(aB[0]); s_g[bB][n2 + 1] = gelu_ex(aB[1]);
        }
        __syncthreads();
        {  // t2 = z @ w2_0 + b2_0
            float aA[1] = {h_b2}, aB[1] = {h_b2};
            mv<1, 128, 64>(aA, aB, &s_g[bA][0], &s_g[bB][0], s_w2 + n1);
            s_g[bA][128 + n1] = aA[0];
            s_g[bB][128 + n1] = aB[0];
        }
        __syncthreads();
        {  // LN chain 0 + inp -> global
            float v0 = s_g[ub][128 + uj], v1 = s_g[ub][128 + uj + 1];
            float m = redsum32(v0 + v1) * (1.0f / 64.0f);
            float var = redsum32(v0 * v0 + v1 * v1) * (1.0f / 64.0f) - m * m;
            float rs = rsqrtf(fmaxf(var, 0.0f) + 1e-5f);
            float a0 = (v0 - m) * rs * h_lag0[0] + h_lab0[0];
            float a1 = (v1 - m) * rs * h_lag0[1] + h_lab0[1];
            float y0 = a0 + s_in0[ub][12 + uj];
            float y1 = a1 + s_in0[ub][12 + uj + 1];
            float m2 = redsum32(y0 + y1) * (1.0f / 64.0f);
            float var2 = redsum32(y0 * y0 + y1 * y1) * (1.0f / 64.0f) - m2 * m2;
            float rs2 = rsqrtf(fmaxf(var2, 0.0f) + 1e-5f);
            float h0n0 = (y0 - m2) * rs2 * h_log0[0] + h_lob0[0];
            float h0n1 = (y1 - m2) * rs2 * h_log0[1] + h_lob0[1];
            s_in0[ub][12 + uj] = h0n0;
            s_in0[ub][12 + uj + 1] = h0n1;
            float p0 = h0n0 + h_rb0[0], p1 = h0n1 + h_rb0[1];
#pragma unroll
            for (int d = 0; d < 12; d++) {
                float xv = s_in0[ub][d];
                p0 = fmaf(xv, h_rw0[d][0], p0);
                p1 = fmaf(xv, h_rw0[d][1], p1);
            }
            float2 pr; pr.x = p0; pr.y = p1;
            *(float2*)(inp_c + (((size_t)(sIdx * Bn + gbase + ub)) * CT + tt) * 64 + uj) = pr;
        }
        __syncthreads();
    }
    // write back state
    for (int i = tid; i < BC * 64; i += 256) {
        int b = i >> 6, j = i & 63;
        float* gs = gstate + ((size_t)(sIdx * Bn + gbase + b)) * 256;
        gs[j] = s_in0[b][12 + j];
        gs[64 + j] = s_c[b][j];
    }
}

// ---------------------------------------------------------------------------
// G1R GEMM: G1R[row][0:256] = inp @ gw1_top + gb1 ; G1R[row][256:320] = inp @ rw1 + rb1
// rows = (s, b*CT+tt). grid = 3*128, block 256, 128 rows/block in 4 tiles of 32.
// ---------------------------------------------------------------------------
__global__ __launch_bounds__(256) void g1r_kernel(
    const float* __restrict__ gw1,   // [3][128][256]
    const float* __restrict__ gb1,   // [3][256]
    const float* __restrict__ rw1,   // [3][64][64]
    const float* __restrict__ rb1,   // [3][64]
    const float* __restrict__ inp_c, // [3][512*CT][64]
    float* __restrict__ G1R) {       // [3][512*CT][320]
    const int tid = threadIdx.x;
    const int s = blockIdx.x >> 7;
    const int rb = blockIdx.x & 127;
    __shared__ __align__(16) float s_W[64 * 320];   // 81920
    __shared__ __align__(16) float s_inT[64][36];   // 9216

    for (int i = tid; i < 64 * 64; i += 256) {      // gw1 top: 64 rows x 256 cols, f4
        int k = i >> 6, cq = i & 63;
        ((float4*)&s_W[k * 320])[cq] = ((const float4*)(gw1 + (size_t)s * 128 * 256 + k * 256))[cq];
    }
    for (int i = tid; i < 64 * 16; i += 256) {      // rw1: 64 x 64, f4
        int k = i >> 4, cq = i & 15;
        ((float4*)&s_W[k * 320 + 256])[cq] = ((const float4*)(rw1 + (size_t)s * 64 * 64 + k * 64))[cq];
    }
    const int c4 = tid & 63, rg = tid >> 6;
    float4 bias = *(const float4*)(gb1 + s * 256 + c4 * 4);
    float rbias = rb1[s * 64 + c4];

    const size_t sRow = (size_t)s * Bn * CT;
    for (int tile = 0; tile < 4; tile++) {
        int r0 = rb * 128 + tile * 32;
        __syncthreads();
        for (int i = tid; i < 512; i += 256) {
            int r = i >> 4, kq = i & 15;
            float4 v = *(const float4*)(inp_c + (sRow + r0 + r) * 64 + kq * 4);
            s_inT[kq * 4 + 0][r] = v.x;
            s_inT[kq * 4 + 1][r] = v.y;
            s_inT[kq * 4 + 2][r] = v.z;
            s_inT[kq * 4 + 3][r] = v.w;
        }
        __syncthreads();
        float acc[8][4], accR[8];
#pragma unroll
        for (int r = 0; r < 8; r++) {
            acc[r][0] = bias.x; acc[r][1] = bias.y; acc[r][2] = bias.z; acc[r][3] = bias.w;
            accR[r] = rbias;
        }
        for (int k = 0; k < 64; k++) {
            float4 w = *(const float4*)&s_W[k * 320 + c4 * 4];
            float wR = s_W[k * 320 + 256 + c4];
            float4 iA = *(const float4*)&s_inT[k][rg * 8];
            float4 iB = *(const float4*)&s_inT[k][rg * 8 + 4];
            float in8[8] = {iA.x, iA.y, iA.z, iA.w, iB.x, iB.y, iB.z, iB.w};
#pragma unroll
            for (int r = 0; r < 8; r++) {
                acc[r][0] = fmaf(in8[r], w.x, acc[r][0]);
                acc[r][1] = fmaf(in8[r], w.y, acc[r][1]);
                acc[r][2] = fmaf(in8[r], w.z, acc[r][2]);
                acc[r][3] = fmaf(in8[r], w.w, acc[r][3]);
                accR[r] = fmaf(in8[r], wR, accR[r]);
            }
        }
#pragma unroll
        for (int r = 0; r < 8; r++) {
            size_t row = sRow + r0 + rg * 8 + r;
            float4 o; o.x = acc[r][0]; o.y = acc[r][1]; o.z = acc[r][2]; o.w = acc[r][3];
            *(float4*)(G1R + row * 320 + c4 * 4) = o;
            G1R[row * 320 + 256 + c4] = accR[r];
        }
    }
}

// ---------------------------------------------------------------------------
// Pass 2: layer 1 over a T-chunk. gw1 h-half + M1_1 + w2_1 LDS-resident;
// inp-part of gates and rw1-residual come precomputed via G1R.
// ---------------------------------------------------------------------------
__global__ __launch_bounds__(256, 1) void pass2_kernel(
    const float* __restrict__ gw1,    // [3][128][256]
    const float* __restrict__ M1g, const float* __restrict__ bias1g,
    const float* __restrict__ w2g, const float* __restrict__ b2g,
    const float* __restrict__ lag, const float* __restrict__ lab,
    const float* __restrict__ log_, const float* __restrict__ lob,
    const float* __restrict__ G1R,    // [3][512*CT][320]
    float* __restrict__ gstate,
    unsigned short* __restrict__ merged_c,  // [3][512][CT][64] bf16
    int t0) {
    const int tid = threadIdx.x;
    const int sIdx = blockIdx.x >> 6;
    const int gbase = (blockIdx.x & 63) * BC;

    __shared__ __align__(16) float s_gw1b[64 * 256];  // 65536
    __shared__ __align__(16) float s_M1[64 * 128];
    __shared__ __align__(16) float s_w2[128 * 64];
    __shared__ float s_h1[BC][80];
    __shared__ float s_g[BC][256];
    __shared__ float s_ht[BC][64];
    __shared__ float s_c[BC][64];
    __shared__ __align__(16) float s_G1R[BC][320];

    {
        const float4* src = (const float4*)(gw1 + (size_t)sIdx * 128 * 256 + 64 * 256);
        for (int i = tid; i < 64 * 256 / 4; i += 256) ((float4*)s_gw1b)[i] = src[i];
        src = (const float4*)(M1g + (sIdx * 2 + 1) * 64 * 128);
        for (int i = tid; i < 64 * 128 / 4; i += 256) ((float4*)s_M1)[i] = src[i];
        src = (const float4*)(w2g + (sIdx * 2 + 1) * 128 * 64);
        for (int i = tid; i < 128 * 64 / 4; i += 256) ((float4*)s_w2)[i] = src[i];
    }
    for (int i = tid; i < BC * 64; i += 256) {
        int b = i >> 6, j = i & 63;
        if (t0 == 0) {
            s_h1[b][j] = 0.f;
            s_c[b][j] = 0.f;
        } else {
            const float* gs = gstate + ((size_t)(sIdx * Bn + gbase + b)) * 256;
            s_h1[b][j] = gs[128 + j];
            s_c[b][j] = gs[192 + j];
        }
    }

    const int cg = tid & 63, bg = tid >> 6;
    const int n4 = cg * 4, n2 = cg * 2, n1 = cg;
    const int bA = bg * 2, bB = bg * 2 + 1;
    const int ub = tid >> 5, uj = (tid & 31) * 2;

    float h_b1[2], h_b2;
    h_b1[0] = bias1g[(sIdx * 2 + 1) * 128 + n2];
    h_b1[1] = bias1g[(sIdx * 2 + 1) * 128 + n2 + 1];
    h_b2 = b2g[(sIdx * 2 + 1) * 64 + n1];
    float h_lag1[2], h_lab1[2], h_log1[2], h_lob1[2];
    {
        int bi = (sIdx * 2 + 1) * 64 + uj;
#pragma unroll
        for (int u = 0; u < 2; u++) {
            h_lag1[u] = lag[bi + u]; h_lab1[u] = lab[bi + u];
            h_log1[u] = log_[bi + u]; h_lob1[u] = lob[bi + u];
        }
    }
    __syncthreads();

    for (int tt = 0; tt < CT; tt++) {
        // stage this step's G1R rows (8 x 320 floats)
        for (int i = tid; i < BC * 80; i += 256) {
            int b = i / 80, q = i % 80;
            ((float4*)&s_G1R[b][0])[q] =
                ((const float4*)(G1R + (((size_t)(sIdx * Bn + gbase + b)) * CT + tt) * 320))[q];
        }
        __syncthreads();
        {  // gates1 = G1(inp-part+gb1) + h1 @ gw1_bot
            float4 gA = *(const float4*)&s_G1R[bA][n4];
            float4 gB = *(const float4*)&s_G1R[bB][n4];
            float aA[4] = {gA.x, gA.y, gA.z, gA.w};
            float aB[4] = {gB.x, gB.y, gB.z, gB.w};
            mv<4, 64, 256>(aA, aB, &s_h1[bA][0], &s_h1[bB][0], s_gw1b + n4);
            float4 rA; rA.x = aA[0]; rA.y = aA[1]; rA.z = aA[2]; rA.w = aA[3];
            float4 rB; rB.x = aB[0]; rB.y = aB[1]; rB.z = aB[2]; rB.w = aB[3];
            *(float4*)&s_g[bA][n4] = rA;
            *(float4*)&s_g[bB][n4] = rB;
        }
        __syncthreads();
        {  // cell1
            float f0 = s_g[ub][uj], f1 = s_g[ub][uj + 1];
            float i0v = s_g[ub][64 + uj], i1v = s_g[ub][64 + uj + 1];
            float g0 = s_g[ub][128 + uj], g1 = s_g[ub][128 + uj + 1];
            float o0 = s_g[ub][192 + uj], o1 = s_g[ub][192 + uj + 1];
            float c0 = s_c[ub][uj], c1 = s_c[ub][uj + 1];
            float cn0 = sigm(f0) * c0 + sigm(i0v) * tanhf(g0);
            float cn1 = sigm(f1) * c1 + sigm(i1v) * tanhf(g1);
            s_c[ub][uj] = cn0; s_c[ub][uj + 1] = cn1;
            s_ht[ub][uj] = sigm(o0) * tanhf(cn0);
            s_ht[ub][uj + 1] = sigm(o1) * tanhf(cn1);
        }
        __syncthreads();
        {  // z = gelu(ht @ M1_1 + bias1_1)
            float aA[2] = {h_b1[0], h_b1[1]};
            float aB[2] = {h_b1[0], h_b1[1]};
            mv<2, 64, 128>(aA, aB, &s_ht[bA][0], &s_ht[bB][0], s_M1 + n2);
            s_g[bA][n2] = gelu_ex(aA[0]); s_g[bA][n2 + 1] = gelu_ex(aA[1]);
            s_g[bB][n2] = gelu_ex(aB[0]); s_g[bB][n2 + 1] = gelu_ex(aB[1]);
        }
        __syncthreads();
        {  // t2 = z @ w2_1 + b2_1
            float aA[1] = {h_b2}, aB[1] = {h_b2};
            mv<1, 128, 64>(aA, aB, &s_g[bA][0], &s_g[bB][0], s_w2 + n1);
            s_g[bA][128 + n1] = aA[0];
            s_g[bB][128 + n1] = aB[0];
        }
        __syncthreads();
        {  // LN chain 1 -> h1new; out = h1new + R1
            float v0 = s_g[ub][128 + uj], v1 = s_g[ub][128 + uj + 1];
            float m = redsum32(v0 + v1) * (1.0f / 64.0f);
            float var = redsum32(v0 * v0 + v1 * v1) * (1.0f / 64.0f) - m * m;
            float rs = rsqrtf(fmaxf(var, 0.0f) + 1e-5f);
            float a0 = (v0 - m) * rs * h_lag1[0] + h_lab1[0];
            float a1 = (v1 - m) * rs * h_lag1[1] + h_lab1[1];
            float y0 = a0 + s_h1[ub][uj];
            float y1 = a1 + s_h1[ub][uj + 1];
            float m2 = redsum32(y0 + y1) * (1.0f / 64.0f);
            float var2 = redsum32(y0 * y0 + y1 * y1) * (1.0f / 64.0f) - m2 * m2;
            float rs2 = rsqrtf(fmaxf(var2, 0.0f) + 1e-5f);
            float h1n0 = (y0 - m2) * rs2 * h_log1[0] + h_lob1[0];
            float h1n1 = (y1 - m2) * rs2 * h_log1[1] + h_lob1[1];
            s_h1[ub][uj] = h1n0;
            s_h1[ub][uj + 1] = h1n1;
            float o0 = h1n0 + s_G1R[ub][256 + uj];
            float o1 = h1n1 + s_G1R[ub][256 + uj + 1];
            size_t mb = (((size_t)(sIdx * Bn + gbase + ub)) * CT + tt) * 64 + uj;
            merged_c[mb] = f2u(o0);
            merged_c[mb + 1] = f2u(o1);
        }
        __syncthreads();
    }
    for (int i = tid; i < BC * 64; i += 256) {
        int b = i >> 6, j = i & 63;
        float* gs = gstate + ((size_t)(sIdx * Bn + gbase + b)) * 256;
        gs[128 + j] = s_h1[b][j];
        gs[192 + j] = s_c[b][j];
    }
}

// ---------------------------------------------------------------------------
// Combine (per chunk): softmax over scales, weighted sum -> out
// ---------------------------------------------------------------------------
__global__ __launch_bounds__(256) void combine_kernel(
    const unsigned short* __restrict__ merged_c,
    const float* __restrict__ attn_w,
    void* __restrict__ outv, const int* __restrict__ flag, int t0) {
    int wid = (blockIdx.x << 2) + (threadIdx.x >> 6);  // 0..512*CT-1
    int lane = threadIdx.x & 63;
    int b = wid / CT, tt = wid % CT;
    float aw = attn_w[lane];
    size_t stride = (size_t)Bn * CT * 64;
    size_t base = (((size_t)b) * CT + tt) * 64 + lane;
    float m0 = u2f(merged_c[base]);
    float m1 = u2f(merged_c[base + stride]);
    float m2 = u2f(merged_c[base + 2 * stride]);
    float e0 = redsum64(m0 * aw);
    float e1 = redsum64(m1 * aw);
    float e2 = redsum64(m2 * aw);
    float mx = fmaxf(e0, fmaxf(e1, e2));
    float x0 = expf(e0 - mx), x1 = expf(e1 - mx), x2 = expf(e2 - mx);
    float inv = 1.0f / (x0 + x1 + x2);
    float val = (x0 * m0 + x1 * m1 + x2 * m2) * inv;
    size_t ob = (((size_t)b) * Ln + t0 + tt) * 64 + lane;
    if (*flag) ((float*)outv)[ob] = val;
    else ((unsigned short*)outv)[ob] = f2u(val);
}

extern "C" void kernel_launch(void* const* d_in, const int* in_sizes, int n_in,
                              void* d_out, int out_size, void* d_ws, size_t ws_size,
                              hipStream_t stream) {
    (void)out_size; (void)ws_size;
    int* flag = (int*)d_ws;
    float* canon = (float*)((char*)d_ws + 16);

    ConvArgs ca;
    size_t tot = 0;
    unsigned nblocks = 0;
    for (int i = 0; i < NIN; i++) {
        ca.src[i] = d_in[i];
        ca.dstOff[i] = (unsigned)tot;
        unsigned n = (unsigned)in_sizes[i];
        ca.n[i] = n;
        ca.blockStart[i] = nblocks;
        nblocks += (n + 2047) / 2048;
        tot += n;
    }
    ca.blockStart[NIN] = nblocks;

    size_t canonBytes = (tot * 4 + 15) & ~(size_t)15;
    char* p = (char*)d_ws + 16 + canonBytes;
    float* M1 = (float*)p;       p += (size_t)3 * 2 * 64 * 128 * 4;
    float* bias1 = (float*)p;    p += (size_t)3 * 2 * 128 * 4;
    float* gstate = (float*)p;   p += (size_t)3 * 512 * 4 * 64 * 4;
    float* inp_c = (float*)p;    p += (size_t)3 * 512 * CT * 64 * 4;
    float* G1R = (float*)p;      p += (size_t)3 * 512 * CT * 320 * 4;
    p = (char*)(((uintptr_t)p + 15) & ~(uintptr_t)15);
    unsigned short* merged_c = (unsigned short*)p;  // 3*512*CT*64*2

    const float* x    = canon + ca.dstOff[0];
    const float* gw0  = canon + ca.dstOff[1];
    const float* gb0  = canon + ca.dstOff[2];
    const float* gw1  = canon + ca.dstOff[3];
    const float* gb1  = canon + ca.dstOff[4];
    const float* mi_w = canon + ca.dstOff[5];
    const float* mi_b = canon + ca.dstOff[6];
    const float* mo_w = canon + ca.dstOff[7];
    const float* mo_b = canon + ca.dstOff[8];
    const float* w1   = canon + ca.dstOff[9];
    const float* b1   = canon + ca.dstOff[10];
    const float* w2   = canon + ca.dstOff[11];
    const float* b2   = canon + ca.dstOff[12];
    const float* lag  = canon + ca.dstOff[13];
    const float* lab  = canon + ca.dstOff[14];
    const float* log_ = canon + ca.dstOff[15];
    const float* lob  = canon + ca.dstOff[16];
    const float* rw0  = canon + ca.dstOff[17];
    const float* rb0  = canon + ca.dstOff[18];
    const float* rw1  = canon + ca.dstOff[19];
    const float* rb1  = canon + ca.dstOff[20];
    const float* attn_w = canon + ca.dstOff[21];

    detect_kernel<<<dim3(1), dim3(256), 0, stream>>>((const unsigned short*)d_in[0], flag);
    convert_kernel<<<dim3(nblocks), dim3(256), 0, stream>>>(ca, canon, flag);
    fuse_kernel<<<dim3(6), dim3(256), 0, stream>>>(mi_w, mi_b, mo_w, mo_b, w1, b1, M1, bias1);

    for (int c = 0; c < NCHUNK; c++) {
        int t0 = c * CT;
        pass1_kernel<<<dim3(Sn * (Bn / BC)), dim3(256), 0, stream>>>(
            x, gw0, gb0, M1, bias1, w2, b2, lag, lab, log_, lob,
            rw0, rb0, gstate, inp_c, t0);
        g1r_kernel<<<dim3(3 * 128), dim3(256), 0, stream>>>(
            gw1, gb1, rw1, rb1, inp_c, G1R);
        pass2_kernel<<<dim3(Sn * (Bn / BC)), dim3(256), 0, stream>>>(
            gw1, M1, bias1, w2, b2, lag, lab, log_, lob,
            G1R, gstate, merged_c, t0);
        combine_kernel<<<dim3(Bn * CT / 4), dim3(256), 0, stream>>>(
            merged_c, attn_w, d_out, flag, t0);
    }
}

// Round 5
// 7140.799 us; speedup vs baseline: 5.9321x; 1.0615x over previous
//
#include <hip/hip_runtime.h>
#include <hip/hip_bf16.h>
#include <math.h>

// Problem constants
#define Sn 3
#define Hn 64
#define Dn 12
#define Bn 512
#define Ln 512
#define BC 8            // batch elems per workgroup
#define IN0 76          // D + H
#define NIN 22
#define CT 32           // timesteps per chunk
#define NCHUNK (Ln / CT)

using bf16 = __hip_bfloat16;

__device__ __forceinline__ float u2f(unsigned short x) {
    return __uint_as_float(((unsigned int)x) << 16);
}
__device__ __forceinline__ unsigned short f2u(float f) {
    bf16 h = __float2bfloat16(f);
    unsigned short u;
    __builtin_memcpy(&u, &h, 2);
    return u;
}
__device__ __forceinline__ float sigm(float x) { return 1.0f / (1.0f + expf(-x)); }
__device__ __forceinline__ float gelu_ex(float x) { return 0.5f * x * (1.0f + erff(x * 0.70710678118654752f)); }

__device__ __forceinline__ float redsum32(float v) {
    v += __shfl_xor(v, 16, 32);
    v += __shfl_xor(v, 8, 32);
    v += __shfl_xor(v, 4, 32);
    v += __shfl_xor(v, 2, 32);
    v += __shfl_xor(v, 1, 32);
    return v;
}
__device__ __forceinline__ float redsum64(float v) {
    v += __shfl_xor(v, 32, 64);
    v += __shfl_xor(v, 16, 64);
    v += __shfl_xor(v, 8, 64);
    v += __shfl_xor(v, 4, 64);
    v += __shfl_xor(v, 2, 64);
    v += __shfl_xor(v, 1, 64);
    return v;
}

// quad butterfly via DPP (VALU pipe, no LDS): xor1 = quad_perm[1,0,3,2]=0xB1,
// xor2 = quad_perm[2,3,0,1]=0x4E. All 4 lanes of each quad get the full sum.
template <int CTRL>
__device__ __forceinline__ float qp(float v) {
    return __int_as_float(__builtin_amdgcn_update_dpp(0, __float_as_int(v), CTRL, 0xF, 0xF, true));
}
__device__ __forceinline__ float qsum(float v) {
    v += qp<0xB1>(v);
    v += qp<0x4E>(v);
    return v;
}
// octet sum: quad sum + ds_swizzle xor4 (BitMode offset 0x101F)
__device__ __forceinline__ float osum(float v) {
    v = qsum(v);
    v += __int_as_float(__builtin_amdgcn_ds_swizzle(__float_as_int(v), 0x101F));
    return v;
}

// ---------------------------------------------------------------------------
// dtype detection (flag=1 -> inputs fp32). Round-3: inputs ARE fp32.
// ---------------------------------------------------------------------------
__global__ __launch_bounds__(256) void detect_kernel(const unsigned short* __restrict__ xr,
                                                     int* __restrict__ flag) {
    __shared__ int sh[4];
    int tid = threadIdx.x;
    int cnt = 0;
    for (int i = tid; i < 2048; i += 256) {
        unsigned e = (xr[i] >> 7) & 0xFF;
        if (e >= 110 && e <= 133) cnt++;
    }
    for (int o = 32; o > 0; o >>= 1) cnt += __shfl_xor(cnt, o, 64);
    if ((tid & 63) == 0) sh[tid >> 6] = cnt;
    __syncthreads();
    if (tid == 0) {
        int tot = sh[0] + sh[1] + sh[2] + sh[3];
        *flag = (tot < 1640) ? 1 : 0;
    }
}

// ---------------------------------------------------------------------------
// canonicalize all inputs to fp32 in ws
// ---------------------------------------------------------------------------
struct ConvArgs {
    const void* src[NIN];
    unsigned dstOff[NIN];
    unsigned n[NIN];
    unsigned blockStart[NIN + 1];
};

__global__ __launch_bounds__(256) void convert_kernel(ConvArgs a, float* __restrict__ dst,
                                                      const int* __restrict__ flag) {
    int bid = blockIdx.x;
    int i = 0;
    while (i < NIN - 1 && bid >= (int)a.blockStart[i + 1]) i++;
    unsigned lb = (unsigned)bid - a.blockStart[i];
    unsigned base = lb * 2048 + threadIdx.x;
    unsigned n = a.n[i];
    float* d = dst + a.dstOff[i];
    bool isf32 = (*flag != 0);
    const float* sf = (const float*)a.src[i];
    const unsigned short* su = (const unsigned short*)a.src[i];
#pragma unroll
    for (int e = 0; e < 8; e++) {
        unsigned idx = base + e * 256;
        if (idx < n) d[idx] = isf32 ? sf[idx] : u2f(su[idx]);
    }
}

// ---------------------------------------------------------------------------
// Setup: fuse  M1 = (mi_w[:,128:192] @ mo_w) @ w1   [64][128] fp32
//        bias1 = ((mi_b[128:192] @ mo_w + mo_b) @ w1 + b1)  [128] fp32
// ---------------------------------------------------------------------------
__global__ __launch_bounds__(256) void fuse_kernel(
    const float* __restrict__ mi_w, const float* __restrict__ mi_b,
    const float* __restrict__ mo_w, const float* __restrict__ mo_b,
    const float* __restrict__ w1, const float* __restrict__ b1,
    float* __restrict__ M1out, float* __restrict__ bias1out) {
    int sl = blockIdx.x;  // 0..5
    __shared__ float T[64][64];
    __shared__ float bT[64];
    const float* Mv = mi_w + sl * 64 * 192;
    const float* Mo = mo_w + sl * 64 * 64;
    for (int idx = threadIdx.x; idx < 64 * 64; idx += 256) {
        int k = idx >> 6, n = idx & 63;
        float acc = 0.f;
        for (int j = 0; j < 64; j++) acc += Mv[k * 192 + 128 + j] * Mo[j * 64 + n];
        T[k][n] = acc;
    }
    for (int n = threadIdx.x; n < 64; n += 256) {
        float acc = mo_b[sl * 64 + n];
        for (int j = 0; j < 64; j++) acc += mi_b[sl * 192 + 128 + j] * Mo[j * 64 + n];
        bT[n] = acc;
    }
    __syncthreads();
    const float* W1 = w1 + sl * 64 * 128;
    for (int idx = threadIdx.x; idx < 64 * 128; idx += 256) {
        int k = idx >> 7, m = idx & 127;
        float acc = 0.f;
        for (int n = 0; n < 64; n++) acc += T[k][n] * W1[n * 128 + m];
        M1out[sl * 64 * 128 + idx] = acc;
    }
    for (int m = threadIdx.x; m < 128; m += 256) {
        float acc = b1[sl * 128 + m];
        for (int n = 0; n < 64; n++) acc += bT[n] * W1[n * 128 + m];
        bias1out[sl * 128 + m] = acc;
    }
}

// ---------------------------------------------------------------------------
// Pass 1: layer 0 over a T-chunk. Register-resident weights + DPP reductions.
// grid = 3*64, block = 256 (4 waves; wave owns 16 units).
// ---------------------------------------------------------------------------
__global__ __launch_bounds__(256, 1) void pass1_kernel(
    const float* __restrict__ x,      // [512][512][12]
    const float* __restrict__ gw0,    // [3][76][256]
    const float* __restrict__ gb0,    // [3][256]
    const float* __restrict__ M1g,    // [3][2][64][128]
    const float* __restrict__ bias1g, // [3][2][128]
    const float* __restrict__ w2g,    // [3][2][128][64]
    const float* __restrict__ b2g,
    const float* __restrict__ lag, const float* __restrict__ lab,
    const float* __restrict__ log_, const float* __restrict__ lob,
    const float* __restrict__ rw0,    // [3][12][64]
    const float* __restrict__ rb0,    // [3][64]
    float* __restrict__ gstate,       // [3][512][4][64]  (h0,c0,h1,c1)
    float* __restrict__ inp_c,        // [3][512][CT][64]
    int t0) {
    const int tid = threadIdx.x;
    const int sIdx = blockIdx.x >> 6;
    const int gbase = (blockIdx.x & 63) * BC;
    const int W = tid >> 6, lane = tid & 63;
    const int q = lane >> 2, ks = lane & 3;
    const int oct = lane >> 3, ks8 = lane & 7;
    const int j = W * 16 + q;        // unit (quad) for gates/cell
    const int cM = W * 32 + q * 2;   // M1 col pair
    const int uD = W * 16 + oct * 2; // w2 unit pair (octet)
    const int ub = tid >> 5, uj = (tid & 31) * 2;  // LN mapping

    const int Li = (sIdx == 0) ? 170 : (sIdx == 1 ? 512 : 256);
    const int st = (sIdx == 0) ? 342 : (sIdx == 1 ? 0 : 256);
    const float sc = (float)Li / 512.0f;

    __shared__ float s_x[2][BC][12];
    __shared__ float s_h[BC][64];
    __shared__ float s_ht[BC][64];
    __shared__ float s_z[BC][132];
    __shared__ float s_t2[BC][64];
    __shared__ float s_rw0[12 * 64];

    // ---- register weights ----
    const float* gw0s = gw0 + sIdx * IN0 * 256;
    float wx[12], wg[64], wm[32], ww[32];
#pragma unroll
    for (int g = 0; g < 4; g++)
#pragma unroll
        for (int d = 0; d < 3; d++) wx[g * 3 + d] = gw0s[(ks * 3 + d) * 256 + j + 64 * g];
#pragma unroll
    for (int g = 0; g < 4; g++)
#pragma unroll
        for (int kk = 0; kk < 16; kk++) wg[g * 16 + kk] = gw0s[(12 + ks * 16 + kk) * 256 + j + 64 * g];
    const float* M1s = M1g + (sIdx * 2 + 0) * 8192;
#pragma unroll
    for (int cc = 0; cc < 2; cc++)
#pragma unroll
        for (int kk = 0; kk < 16; kk++) wm[cc * 16 + kk] = M1s[(ks * 16 + kk) * 128 + cM + cc];
    const float* w2s = w2g + (sIdx * 2 + 0) * 8192;
#pragma unroll
    for (int cc = 0; cc < 2; cc++)
#pragma unroll
        for (int kk = 0; kk < 16; kk++) ww[cc * 16 + kk] = w2s[(ks8 * 16 + kk) * 64 + uD + cc];

    float h_gb[4];
#pragma unroll
    for (int g = 0; g < 4; g++) h_gb[g] = gb0[sIdx * 256 + j + 64 * g];
    float h_b1[2] = {bias1g[(sIdx * 2 + 0) * 128 + cM], bias1g[(sIdx * 2 + 0) * 128 + cM + 1]};
    float h_b2[2] = {b2g[(sIdx * 2 + 0) * 64 + uD], b2g[(sIdx * 2 + 0) * 64 + uD + 1]};
    float h_lag[2], h_lab[2], h_log[2], h_lob[2], h_rb0[2];
    {
        int bi = (sIdx * 2 + 0) * 64 + uj;
#pragma unroll
        for (int u = 0; u < 2; u++) {
            h_lag[u] = lag[bi + u]; h_lab[u] = lab[bi + u];
            h_log[u] = log_[bi + u]; h_lob[u] = lob[bi + u];
            h_rb0[u] = rb0[sIdx * 64 + uj + u];
        }
    }

    // ---- init LDS / state ----
    for (int i = tid; i < 768; i += 256) s_rw0[i] = rw0[sIdx * 768 + i];
    for (int i = tid; i < BC * 64; i += 256) {
        int b = i >> 6, jj = i & 63;
        s_h[b][jj] = (t0 == 0) ? 0.f : gstate[((size_t)(sIdx * Bn + gbase + b)) * 256 + jj];
    }
    float cS0, cS1;
    if (t0 == 0) { cS0 = 0.f; cS1 = 0.f; }
    else {
        cS0 = gstate[((size_t)(sIdx * Bn + gbase + ks)) * 256 + 64 + j];
        cS1 = gstate[((size_t)(sIdx * Bn + gbase + ks + 4)) * 256 + 64 + j];
    }
    // stage x for tt=0
    if (tid < BC * 12) {
        int b = tid / 12, d = tid % 12;
        float srcp = fmaxf((t0 + 0.5f) * sc - 0.5f, 0.f);
        int i0 = (int)floorf(srcp); if (i0 > Li - 1) i0 = Li - 1;
        int i1 = i0 + 1; if (i1 > Li - 1) i1 = Li - 1;
        float w = srcp - (float)i0;
        int gb = gbase + b;
        s_x[0][b][d] = x[(gb * Ln + st + i0) * 12 + d] * (1.0f - w) + x[(gb * Ln + st + i1) * 12 + d] * w;
    }
    __syncthreads();

    for (int tt = 0; tt < CT; tt++) {
        const int sl = tt & 1;
        // ===== A: gates0 (x-part + h-part) + cell =====
        float myF0 = 0, myI0 = 0, myG0 = 0, myO0 = 0, myF1 = 0, myI1 = 0, myG1 = 0, myO1 = 0;
#pragma unroll
        for (int b = 0; b < 8; b++) {
            const float4* hp = (const float4*)&s_h[b][ks * 16];
            float4 hv0 = hp[0], hv1 = hp[1], hv2 = hp[2], hv3 = hp[3];
            float x0 = s_x[sl][b][ks * 3], x1 = s_x[sl][b][ks * 3 + 1], x2 = s_x[sl][b][ks * 3 + 2];
            float a0 = (ks == 0) ? h_gb[0] : 0.f;
            float a1 = (ks == 0) ? h_gb[1] : 0.f;
            float a2 = (ks == 0) ? h_gb[2] : 0.f;
            float a3 = (ks == 0) ? h_gb[3] : 0.f;
            a0 = fmaf(wx[0], x0, fmaf(wx[1], x1, fmaf(wx[2], x2, a0)));
            a1 = fmaf(wx[3], x0, fmaf(wx[4], x1, fmaf(wx[5], x2, a1)));
            a2 = fmaf(wx[6], x0, fmaf(wx[7], x1, fmaf(wx[8], x2, a2)));
            a3 = fmaf(wx[9], x0, fmaf(wx[10], x1, fmaf(wx[11], x2, a3)));
            float hk[16] = {hv0.x, hv0.y, hv0.z, hv0.w, hv1.x, hv1.y, hv1.z, hv1.w,
                            hv2.x, hv2.y, hv2.z, hv2.w, hv3.x, hv3.y, hv3.z, hv3.w};
#pragma unroll
            for (int kk = 0; kk < 16; kk++) {
                a0 = fmaf(wg[kk], hk[kk], a0);
                a1 = fmaf(wg[16 + kk], hk[kk], a1);
                a2 = fmaf(wg[32 + kk], hk[kk], a2);
                a3 = fmaf(wg[48 + kk], hk[kk], a3);
            }
            a0 = qsum(a0); a1 = qsum(a1); a2 = qsum(a2); a3 = qsum(a3);
            bool mine = ((b & 3) == ks);
            if (b < 4) { if (mine) { myF0 = a0; myI0 = a1; myG0 = a2; myO0 = a3; } }
            else       { if (mine) { myF1 = a0; myI1 = a1; myG1 = a2; myO1 = a3; } }
        }
        {
            float cn0 = sigm(myF0) * cS0 + sigm(myI0) * tanhf(myG0);
            cS0 = cn0;
            s_ht[ks][j] = sigm(myO0) * tanhf(cn0);
            float cn1 = sigm(myF1) * cS1 + sigm(myI1) * tanhf(myG1);
            cS1 = cn1;
            s_ht[ks + 4][j] = sigm(myO1) * tanhf(cn1);
        }
        __syncthreads();
        // ===== C: z = gelu(ht @ M1_0 + bias1) =====
        float z00 = 0, z01 = 0, z10 = 0, z11 = 0;
#pragma unroll
        for (int b = 0; b < 8; b++) {
            const float4* hp = (const float4*)&s_ht[b][ks * 16];
            float4 hv0 = hp[0], hv1 = hp[1], hv2 = hp[2], hv3 = hp[3];
            float a0 = (ks == 0) ? h_b1[0] : 0.f;
            float a1 = (ks == 0) ? h_b1[1] : 0.f;
            float hk[16] = {hv0.x, hv0.y, hv0.z, hv0.w, hv1.x, hv1.y, hv1.z, hv1.w,
                            hv2.x, hv2.y, hv2.z, hv2.w, hv3.x, hv3.y, hv3.z, hv3.w};
#pragma unroll
            for (int kk = 0; kk < 16; kk++) {
                a0 = fmaf(wm[kk], hk[kk], a0);
                a1 = fmaf(wm[16 + kk], hk[kk], a1);
            }
            a0 = qsum(a0); a1 = qsum(a1);
            bool mine = ((b & 3) == ks);
            if (b < 4) { if (mine) { z00 = a0; z01 = a1; } }
            else       { if (mine) { z10 = a0; z11 = a1; } }
        }
        s_z[ks][cM] = gelu_ex(z00); s_z[ks][cM + 1] = gelu_ex(z01);
        s_z[ks + 4][cM] = gelu_ex(z10); s_z[ks + 4][cM + 1] = gelu_ex(z11);
        __syncthreads();
        // ===== D: t2 = z @ w2_0 + b2 (octet) =====
#pragma unroll
        for (int b = 0; b < 8; b++) {
            const float4* zp = (const float4*)&s_z[b][ks8 * 16];
            float4 zv0 = zp[0], zv1 = zp[1], zv2 = zp[2], zv3 = zp[3];
            float a0 = (ks8 == 0) ? h_b2[0] : 0.f;
            float a1 = (ks8 == 0) ? h_b2[1] : 0.f;
            float zk[16] = {zv0.x, zv0.y, zv0.z, zv0.w, zv1.x, zv1.y, zv1.z, zv1.w,
                            zv2.x, zv2.y, zv2.z, zv2.w, zv3.x, zv3.y, zv3.z, zv3.w};
#pragma unroll
            for (int kk = 0; kk < 16; kk++) {
                a0 = fmaf(ww[kk], zk[kk], a0);
                a1 = fmaf(ww[16 + kk], zk[kk], a1);
            }
            a0 = osum(a0); a1 = osum(a1);
            if (b == ks8) { s_t2[b][uD] = a0; s_t2[b][uD + 1] = a1; }
        }
        __syncthreads();
        // ===== E: LN chain + inp =====
        {
            float v0 = s_t2[ub][uj], v1 = s_t2[ub][uj + 1];
            float m = redsum32(v0 + v1) * (1.0f / 64.0f);
            float var = redsum32(v0 * v0 + v1 * v1) * (1.0f / 64.0f) - m * m;
            float rs = rsqrtf(fmaxf(var, 0.0f) + 1e-5f);
            float a0 = (v0 - m) * rs * h_lag[0] + h_lab[0];
            float a1 = (v1 - m) * rs * h_lag[1] + h_lab[1];
            float y0 = a0 + s_h[ub][uj];
            float y1 = a1 + s_h[ub][uj + 1];
            float m2 = redsum32(y0 + y1) * (1.0f / 64.0f);
            float var2 = redsum32(y0 * y0 + y1 * y1) * (1.0f / 64.0f) - m2 * m2;
            float rs2 = rsqrtf(fmaxf(var2, 0.0f) + 1e-5f);
            float h0n0 = (y0 - m2) * rs2 * h_log[0] + h_lob[0];
            float h0n1 = (y1 - m2) * rs2 * h_log[1] + h_lob[1];
            s_h[ub][uj] = h0n0;
            s_h[ub][uj + 1] = h0n1;
            float p0 = h0n0 + h_rb0[0], p1 = h0n1 + h_rb0[1];
#pragma unroll
            for (int d = 0; d < 12; d++) {
                float xv = s_x[sl][ub][d];
                p0 = fmaf(xv, s_rw0[d * 64 + uj], p0);
                p1 = fmaf(xv, s_rw0[d * 64 + uj + 1], p1);
            }
            float2 pr; pr.x = p0; pr.y = p1;
            *(float2*)(inp_c + (((size_t)(sIdx * Bn + gbase + ub)) * CT + tt) * 64 + uj) = pr;
        }
        // stage x for tt+1 (other slot — no race with readers of slot sl)
        if (tt + 1 < CT && tid < BC * 12) {
            int b = tid / 12, d = tid % 12;
            int t = t0 + tt + 1;
            float srcp = fmaxf((t + 0.5f) * sc - 0.5f, 0.f);
            int i0 = (int)floorf(srcp); if (i0 > Li - 1) i0 = Li - 1;
            int i1 = i0 + 1; if (i1 > Li - 1) i1 = Li - 1;
            float w = srcp - (float)i0;
            int gb = gbase + b;
            s_x[sl ^ 1][b][d] = x[(gb * Ln + st + i0) * 12 + d] * (1.0f - w) + x[(gb * Ln + st + i1) * 12 + d] * w;
        }
        __syncthreads();
    }
    // ---- writeback state ----
    for (int i = tid; i < BC * 64; i += 256) {
        int b = i >> 6, jj = i & 63;
        gstate[((size_t)(sIdx * Bn + gbase + b)) * 256 + jj] = s_h[b][jj];
    }
    gstate[((size_t)(sIdx * Bn + gbase + ks)) * 256 + 64 + j] = cS0;
    gstate[((size_t)(sIdx * Bn + gbase + ks + 4)) * 256 + 64 + j] = cS1;
}

// ---------------------------------------------------------------------------
// G1R GEMM: G1R[row][0:256] = inp @ gw1_top + gb1 ; [256:320] = inp @ rw1 + rb1
// ---------------------------------------------------------------------------
__global__ __launch_bounds__(256) void g1r_kernel(
    const float* __restrict__ gw1,   // [3][128][256]
    const float* __restrict__ gb1,   // [3][256]
    const float* __restrict__ rw1,   // [3][64][64]
    const float* __restrict__ rb1,   // [3][64]
    const float* __restrict__ inp_c, // [3][512*CT][64]
    float* __restrict__ G1R) {       // [3][512*CT][320]
    const int tid = threadIdx.x;
    const int s = blockIdx.x >> 7;
    const int rb = blockIdx.x & 127;
    __shared__ __align__(16) float s_W[64 * 320];
    __shared__ __align__(16) float s_inT[64][36];

    for (int i = tid; i < 64 * 64; i += 256) {
        int k = i >> 6, cq = i & 63;
        ((float4*)&s_W[k * 320])[cq] = ((const float4*)(gw1 + (size_t)s * 128 * 256 + k * 256))[cq];
    }
    for (int i = tid; i < 64 * 16; i += 256) {
        int k = i >> 4, cq = i & 15;
        ((float4*)&s_W[k * 320 + 256])[cq] = ((const float4*)(rw1 + (size_t)s * 64 * 64 + k * 64))[cq];
    }
    const int c4 = tid & 63, rg = tid >> 6;
    float4 bias = *(const float4*)(gb1 + s * 256 + c4 * 4);
    float rbias = rb1[s * 64 + c4];

    const size_t sRow = (size_t)s * Bn * CT;
    for (int tile = 0; tile < 4; tile++) {
        int r0 = rb * 128 + tile * 32;
        __syncthreads();
        for (int i = tid; i < 512; i += 256) {
            int r = i >> 4, kq = i & 15;
            float4 v = *(const float4*)(inp_c + (sRow + r0 + r) * 64 + kq * 4);
            s_inT[kq * 4 + 0][r] = v.x;
            s_inT[kq * 4 + 1][r] = v.y;
            s_inT[kq * 4 + 2][r] = v.z;
            s_inT[kq * 4 + 3][r] = v.w;
        }
        __syncthreads();
        float acc[8][4], accR[8];
#pragma unroll
        for (int r = 0; r < 8; r++) {
            acc[r][0] = bias.x; acc[r][1] = bias.y; acc[r][2] = bias.z; acc[r][3] = bias.w;
            accR[r] = rbias;
        }
        for (int k = 0; k < 64; k++) {
            float4 w = *(const float4*)&s_W[k * 320 + c4 * 4];
            float wR = s_W[k * 320 + 256 + c4];
            float4 iA = *(const float4*)&s_inT[k][rg * 8];
            float4 iB = *(const float4*)&s_inT[k][rg * 8 + 4];
            float in8[8] = {iA.x, iA.y, iA.z, iA.w, iB.x, iB.y, iB.z, iB.w};
#pragma unroll
            for (int r = 0; r < 8; r++) {
                acc[r][0] = fmaf(in8[r], w.x, acc[r][0]);
                acc[r][1] = fmaf(in8[r], w.y, acc[r][1]);
                acc[r][2] = fmaf(in8[r], w.z, acc[r][2]);
                acc[r][3] = fmaf(in8[r], w.w, acc[r][3]);
                accR[r] = fmaf(in8[r], wR, accR[r]);
            }
        }
#pragma unroll
        for (int r = 0; r < 8; r++) {
            size_t row = sRow + r0 + rg * 8 + r;
            float4 o; o.x = acc[r][0]; o.y = acc[r][1]; o.z = acc[r][2]; o.w = acc[r][3];
            *(float4*)(G1R + row * 320 + c4 * 4) = o;
            G1R[row * 320 + 256 + c4] = accR[r];
        }
    }
}

// ---------------------------------------------------------------------------
// Pass 2: layer 1 over a T-chunk. Register weights + DPP reductions.
// ---------------------------------------------------------------------------
__global__ __launch_bounds__(256, 1) void pass2_kernel(
    const float* __restrict__ gw1,    // [3][128][256]
    const float* __restrict__ M1g, const float* __restrict__ bias1g,
    const float* __restrict__ w2g, const float* __restrict__ b2g,
    const float* __restrict__ lag, const float* __restrict__ lab,
    const float* __restrict__ log_, const float* __restrict__ lob,
    const float* __restrict__ G1R,    // [3][512*CT][320]
    float* __restrict__ gstate,
    unsigned short* __restrict__ merged_c,  // [3][512][CT][64] bf16
    int t0) {
    const int tid = threadIdx.x;
    const int sIdx = blockIdx.x >> 6;
    const int gbase = (blockIdx.x & 63) * BC;
    const int W = tid >> 6, lane = tid & 63;
    const int q = lane >> 2, ks = lane & 3;
    const int oct = lane >> 3, ks8 = lane & 7;
    const int j = W * 16 + q;
    const int cM = W * 32 + q * 2;
    const int uD = W * 16 + oct * 2;
    const int ub = tid >> 5, uj = (tid & 31) * 2;

    __shared__ float s_h[BC][64];
    __shared__ float s_ht[BC][64];
    __shared__ float s_z[BC][132];
    __shared__ float s_t2[BC][64];
    __shared__ __align__(16) float s_G1R[BC][320];

    // ---- register weights ----
    const float* gw1s = gw1 + (size_t)sIdx * 128 * 256;
    float wg[64], wm[32], ww[32];
#pragma unroll
    for (int g = 0; g < 4; g++)
#pragma unroll
        for (int kk = 0; kk < 16; kk++) wg[g * 16 + kk] = gw1s[(64 + ks * 16 + kk) * 256 + j + 64 * g];
    const float* M1s = M1g + (sIdx * 2 + 1) * 8192;
#pragma unroll
    for (int cc = 0; cc < 2; cc++)
#pragma unroll
        for (int kk = 0; kk < 16; kk++) wm[cc * 16 + kk] = M1s[(ks * 16 + kk) * 128 + cM + cc];
    const float* w2s = w2g + (sIdx * 2 + 1) * 8192;
#pragma unroll
    for (int cc = 0; cc < 2; cc++)
#pragma unroll
        for (int kk = 0; kk < 16; kk++) ww[cc * 16 + kk] = w2s[(ks8 * 16 + kk) * 64 + uD + cc];

    float h_b1[2] = {bias1g[(sIdx * 2 + 1) * 128 + cM], bias1g[(sIdx * 2 + 1) * 128 + cM + 1]};
    float h_b2[2] = {b2g[(sIdx * 2 + 1) * 64 + uD], b2g[(sIdx * 2 + 1) * 64 + uD + 1]};
    float h_lag[2], h_lab[2], h_log[2], h_lob[2];
    {
        int bi = (sIdx * 2 + 1) * 64 + uj;
#pragma unroll
        for (int u = 0; u < 2; u++) {
            h_lag[u] = lag[bi + u]; h_lab[u] = lab[bi + u];
            h_log[u] = log_[bi + u]; h_lob[u] = lob[bi + u];
        }
    }

    // ---- init ----
    for (int i = tid; i < BC * 64; i += 256) {
        int b = i >> 6, jj = i & 63;
        s_h[b][jj] = (t0 == 0) ? 0.f : gstate[((size_t)(sIdx * Bn + gbase + b)) * 256 + 128 + jj];
    }
    float cS0, cS1;
    if (t0 == 0) { cS0 = 0.f; cS1 = 0.f; }
    else {
        cS0 = gstate[((size_t)(sIdx * Bn + gbase + ks)) * 256 + 192 + j];
        cS1 = gstate[((size_t)(sIdx * Bn + gbase + ks + 4)) * 256 + 192 + j];
    }
    // stage G1R for tt=0
    for (int i = tid; i < BC * 80; i += 256) {
        int b = i / 80, qd = i % 80;
        ((float4*)&s_G1R[b][0])[qd] =
            ((const float4*)(G1R + (((size_t)(sIdx * Bn + gbase + b)) * CT + 0) * 320))[qd];
    }
    __syncthreads();

    for (int tt = 0; tt < CT; tt++) {
        // ===== A: gates1 = G1R(inp-part,+gb1) + h1 @ gw1_bot; cell =====
        float myF0 = 0, myI0 = 0, myG0 = 0, myO0 = 0, myF1 = 0, myI1 = 0, myG1 = 0, myO1 = 0;
#pragma unroll
        for (int b = 0; b < 8; b++) {
            const float4* hp = (const float4*)&s_h[b][ks * 16];
            float4 hv0 = hp[0], hv1 = hp[1], hv2 = hp[2], hv3 = hp[3];
            float g1r = s_G1R[b][j + ks * 64];
            float a0 = (ks == 0) ? g1r : 0.f;
            float a1 = (ks == 1) ? g1r : 0.f;
            float a2 = (ks == 2) ? g1r : 0.f;
            float a3 = (ks == 3) ? g1r : 0.f;
            float hk[16] = {hv0.x, hv0.y, hv0.z, hv0.w, hv1.x, hv1.y, hv1.z, hv1.w,
                            hv2.x, hv2.y, hv2.z, hv2.w, hv3.x, hv3.y, hv3.z, hv3.w};
#pragma unroll
            for (int kk = 0; kk < 16; kk++) {
                a0 = fmaf(wg[kk], hk[kk], a0);
                a1 = fmaf(wg[16 + kk], hk[kk], a1);
                a2 = fmaf(wg[32 + kk], hk[kk], a2);
                a3 = fmaf(wg[48 + kk], hk[kk], a3);
            }
            a0 = qsum(a0); a1 = qsum(a1); a2 = qsum(a2); a3 = qsum(a3);
            bool mine = ((b & 3) == ks);
            if (b < 4) { if (mine) { myF0 = a0; myI0 = a1; myG0 = a2; myO0 = a3; } }
            else       { if (mine) { myF1 = a0; myI1 = a1; myG1 = a2; myO1 = a3; } }
        }
        {
            float cn0 = sigm(myF0) * cS0 + sigm(myI0) * tanhf(myG0);
            cS0 = cn0;
            s_ht[ks][j] = sigm(myO0) * tanhf(cn0);
            float cn1 = sigm(myF1) * cS1 + sigm(myI1) * tanhf(myG1);
            cS1 = cn1;
            s_ht[ks + 4][j] = sigm(myO1) * tanhf(cn1);
        }
        __syncthreads();
        // ===== C: z = gelu(ht @ M1_1 + bias1) =====
        float z00 = 0, z01 = 0, z10 = 0, z11 = 0;
#pragma unroll
        for (int b = 0; b < 8; b++) {
            const float4* hp = (const float4*)&s_ht[b][ks * 16];
            float4 hv0 = hp[0], hv1 = hp[1], hv2 = hp[2], hv3 = hp[3];
            float a0 = (ks == 0) ? h_b1[0] : 0.f;
            float a1 = (ks == 0) ? h_b1[1] : 0.f;
            float hk[16] = {hv0.x, hv0.y, hv0.z, hv0.w, hv1.x, hv1.y, hv1.z, hv1.w,
                            hv2.x, hv2.y, hv2.z, hv2.w, hv3.x, hv3.y, hv3.z, hv3.w};
#pragma unroll
            for (int kk = 0; kk < 16; kk++) {
                a0 = fmaf(wm[kk], hk[kk], a0);
                a1 = fmaf(wm[16 + kk], hk[kk], a1);
            }
            a0 = qsum(a0); a1 = qsum(a1);
            bool mine = ((b & 3) == ks);
            if (b < 4) { if (mine) { z00 = a0; z01 = a1; } }
            else       { if (mine) { z10 = a0; z11 = a1; } }
        }
        s_z[ks][cM] = gelu_ex(z00); s_z[ks][cM + 1] = gelu_ex(z01);
        s_z[ks + 4][cM] = gelu_ex(z10); s_z[ks + 4][cM + 1] = gelu_ex(z11);
        __syncthreads();
        // ===== D: t2 = z @ w2_1 + b2 (octet); hoist R1 residual =====
#pragma unroll
        for (int b = 0; b < 8; b++) {
            const float4* zp = (const float4*)&s_z[b][ks8 * 16];
            float4 zv0 = zp[0], zv1 = zp[1], zv2 = zp[2], zv3 = zp[3];
            float a0 = (ks8 == 0) ? h_b2[0] : 0.f;
            float a1 = (ks8 == 0) ? h_b2[1] : 0.f;
            float zk[16] = {zv0.x, zv0.y, zv0.z, zv0.w, zv1.x, zv1.y, zv1.z, zv1.w,
                            zv2.x, zv2.y, zv2.z, zv2.w, zv3.x, zv3.y, zv3.z, zv3.w};
#pragma unroll
            for (int kk = 0; kk < 16; kk++) {
                a0 = fmaf(ww[kk], zk[kk], a0);
                a1 = fmaf(ww[16 + kk], zk[kk], a1);
            }
            a0 = osum(a0); a1 = osum(a1);
            if (b == ks8) { s_t2[b][uD] = a0; s_t2[b][uD + 1] = a1; }
        }
        float rA = s_G1R[ub][256 + uj], rB = s_G1R[ub][256 + uj + 1];
        __syncthreads();
        // ===== E: LN chain -> h1new; out = h1new + R1; stage next G1R =====
        {
            float v0 = s_t2[ub][uj], v1 = s_t2[ub][uj + 1];
            float m = redsum32(v0 + v1) * (1.0f / 64.0f);
            float var = redsum32(v0 * v0 + v1 * v1) * (1.0f / 64.0f) - m * m;
            float rs = rsqrtf(fmaxf(var, 0.0f) + 1e-5f);
            float a0 = (v0 - m) * rs * h_lag[0] + h_lab[0];
            float a1 = (v1 - m) * rs * h_lag[1] + h_lab[1];
            float y0 = a0 + s_h[ub][uj];
            float y1 = a1 + s_h[ub][uj + 1];
            float m2 = redsum32(y0 + y1) * (1.0f / 64.0f);
            float var2 = redsum32(y0 * y0 + y1 * y1) * (1.0f / 64.0f) - m2 * m2;
            float rs2 = rsqrtf(fmaxf(var2, 0.0f) + 1e-5f);
            float h1n0 = (y0 - m2) * rs2 * h_log[0] + h_lob[0];
            float h1n1 = (y1 - m2) * rs2 * h_log[1] + h_lob[1];
            s_h[ub][uj] = h1n0;
            s_h[ub][uj + 1] = h1n1;
            size_t mb = (((size_t)(sIdx * Bn + gbase + ub)) * CT + tt) * 64 + uj;
            merged_c[mb] = f2u(h1n0 + rA);
            merged_c[mb + 1] = f2u(h1n1 + rB);
        }
        if (tt + 1 < CT) {
            for (int i = tid; i < BC * 80; i += 256) {
                int b = i / 80, qd = i % 80;
                ((float4*)&s_G1R[b][0])[qd] =
                    ((const float4*)(G1R + (((size_t)(sIdx * Bn + gbase + b)) * CT + (tt + 1)) * 320))[qd];
            }
        }
        __syncthreads();
    }
    // ---- writeback state ----
    for (int i = tid; i < BC * 64; i += 256) {
        int b = i >> 6, jj = i & 63;
        gstate[((size_t)(sIdx * Bn + gbase + b)) * 256 + 128 + jj] = s_h[b][jj];
    }
    gstate[((size_t)(sIdx * Bn + gbase + ks)) * 256 + 192 + j] = cS0;
    gstate[((size_t)(sIdx * Bn + gbase + ks + 4)) * 256 + 192 + j] = cS1;
}

// ---------------------------------------------------------------------------
// Combine (per chunk): softmax over scales, weighted sum -> out
// ---------------------------------------------------------------------------
__global__ __launch_bounds__(256) void combine_kernel(
    const unsigned short* __restrict__ merged_c,
    const float* __restrict__ attn_w,
    void* __restrict__ outv, const int* __restrict__ flag, int t0) {
    int wid = (blockIdx.x << 2) + (threadIdx.x >> 6);
    int lane = threadIdx.x & 63;
    int b = wid / CT, tt = wid % CT;
    float aw = attn_w[lane];
    size_t stride = (size_t)Bn * CT * 64;
    size_t base = (((size_t)b) * CT + tt) * 64 + lane;
    float m0 = u2f(merged_c[base]);
    float m1 = u2f(merged_c[base + stride]);
    float m2 = u2f(merged_c[base + 2 * stride]);
    float e0 = redsum64(m0 * aw);
    float e1 = redsum64(m1 * aw);
    float e2 = redsum64(m2 * aw);
    float mx = fmaxf(e0, fmaxf(e1, e2));
    float x0 = expf(e0 - mx), x1 = expf(e1 - mx), x2 = expf(e2 - mx);
    float inv = 1.0f / (x0 + x1 + x2);
    float val = (x0 * m0 + x1 * m1 + x2 * m2) * inv;
    size_t ob = (((size_t)b) * Ln + t0 + tt) * 64 + lane;
    if (*flag) ((float*)outv)[ob] = val;
    else ((unsigned short*)outv)[ob] = f2u(val);
}

extern "C" void kernel_launch(void* const* d_in, const int* in_sizes, int n_in,
                              void* d_out, int out_size, void* d_ws, size_t ws_size,
                              hipStream_t stream) {
    (void)out_size; (void)ws_size;
    int* flag = (int*)d_ws;
    float* canon = (float*)((char*)d_ws + 16);

    ConvArgs ca;
    size_t tot = 0;
    unsigned nblocks = 0;
    for (int i = 0; i < NIN; i++) {
        ca.src[i] = d_in[i];
        ca.dstOff[i] = (unsigned)tot;
        unsigned n = (unsigned)in_sizes[i];
        ca.n[i] = n;
        ca.blockStart[i] = nblocks;
        nblocks += (n + 2047) / 2048;
        tot += n;
    }
    ca.blockStart[NIN] = nblocks;

    size_t canonBytes = (tot * 4 + 15) & ~(size_t)15;
    char* p = (char*)d_ws + 16 + canonBytes;
    float* M1 = (float*)p;       p += (size_t)3 * 2 * 64 * 128 * 4;
    float* bias1 = (float*)p;    p += (size_t)3 * 2 * 128 * 4;
    float* gstate = (float*)p;   p += (size_t)3 * 512 * 4 * 64 * 4;
    float* inp_c = (float*)p;    p += (size_t)3 * 512 * CT * 64 * 4;
    float* G1R = (float*)p;      p += (size_t)3 * 512 * CT * 320 * 4;
    p = (char*)(((uintptr_t)p + 15) & ~(uintptr_t)15);
    unsigned short* merged_c = (unsigned short*)p;

    const float* x    = canon + ca.dstOff[0];
    const float* gw0  = canon + ca.dstOff[1];
    const float* gb0  = canon + ca.dstOff[2];
    const float* gw1  = canon + ca.dstOff[3];
    const float* gb1  = canon + ca.dstOff[4];
    const float* mi_w = canon + ca.dstOff[5];
    const float* mi_b = canon + ca.dstOff[6];
    const float* mo_w = canon + ca.dstOff[7];
    const float* mo_b = canon + ca.dstOff[8];
    const float* w1   = canon + ca.dstOff[9];
    const float* b1   = canon + ca.dstOff[10];
    const float* w2   = canon + ca.dstOff[11];
    const float* b2   = canon + ca.dstOff[12];
    const float* lag  = canon + ca.dstOff[13];
    const float* lab  = canon + ca.dstOff[14];
    const float* log_ = canon + ca.dstOff[15];
    const float* lob  = canon + ca.dstOff[16];
    const float* rw0  = canon + ca.dstOff[17];
    const float* rb0  = canon + ca.dstOff[18];
    const float* rw1  = canon + ca.dstOff[19];
    const float* rb1  = canon + ca.dstOff[20];
    const float* attn_w = canon + ca.dstOff[21];

    detect_kernel<<<dim3(1), dim3(256), 0, stream>>>((const unsigned short*)d_in[0], flag);
    convert_kernel<<<dim3(nblocks), dim3(256), 0, stream>>>(ca, canon, flag);
    fuse_kernel<<<dim3(6), dim3(256), 0, stream>>>(mi_w, mi_b, mo_w, mo_b, w1, b1, M1, bias1);

    for (int c = 0; c < NCHUNK; c++) {
        int t0 = c * CT;
        pass1_kernel<<<dim3(Sn * (Bn / BC)), dim3(256), 0, stream>>>(
            x, gw0, gb0, M1, bias1, w2, b2, lag, lab, log_, lob,
            rw0, rb0, gstate, inp_c, t0);
        g1r_kernel<<<dim3(3 * 128), dim3(256), 0, stream>>>(
            gw1, gb1, rw1, rb1, inp_c, G1R);
        pass2_kernel<<<dim3(Sn * (Bn / BC)), dim3(256), 0, stream>>>(
            gw1, M1, bias1, w2, b2, lag, lab, log_, lob,
            G1R, gstate, merged_c, t0);
        combine_kernel<<<dim3(Bn * CT / 4), dim3(256), 0, stream>>>(
            merged_c, attn_w, d_out, flag, t0);
    }
}